// Round 2
// baseline (605.258 us; speedup 1.0000x reference)
//
#include <hip/hip_runtime.h>
#include <stdint.h>

// ---------------------------------------------------------------------------
// d128snn_delays, round 2: low-rank DCLS.
// K_norm(p,l) = exp(-(l'-p)^2/288)/S(p), l'=l-12. Expand exp(l'p/144) in a
// 6-term Taylor (|l'p/144|<=1, trunc err <=1.6e-3 rel):
//   K_norm ~= sum_r phi_r(l) * c_r(p),  phi_r(l)=exp(-l'^2/288)(l'/12)^r,
//   c_r(p)=exp(-p^2/288)(p/12)^r/(r! * (S(p)+1e-7)).
// Per layer: Z_r = X @ W_r^T (one plain GEMM, N = 6*Cout), then
//   y[t] = sum_r sum_tau phi_r(tau) Z_r[t+tau-24]   (25-tap FIR, literals).
// No delay shifts in the GEMM, no atomics, grid = 100 x 12 blocks.
// ---------------------------------------------------------------------------

#define T_LEN 100
#define B_SZ  128
#define M_ROWS 12800
#define R_RANK 6

typedef __bf16 v8bf __attribute__((ext_vector_type(8)));
typedef float  v4f  __attribute__((ext_vector_type(4)));

// compile-time FIR coefficient table: PHI[tau][r] = exp(-l'^2/288) * (l'/12)^r
struct PhiT { float v[25][R_RANK]; };
constexpr double cexp_(double x) {
  double s = 1.0, t = 1.0;
  for (int n = 1; n < 30; ++n) { t = t * x / n; s += t; }
  return s;
}
constexpr PhiT make_phi() {
  PhiT P{};
  for (int tau = 0; tau < 25; ++tau) {
    double lp = (tau - 12) / 12.0;
    double g = cexp_(-0.5 * lp * lp);
    double m = 1.0;
    for (int r = 0; r < R_RANK; ++r) { P.v[tau][r] = (float)(g * m); m *= lp; }
  }
  return P;
}
constexpr PhiT PHI = make_phi();

__device__ __forceinline__ void gl_lds16(const void* g, void* l) {
  __builtin_amdgcn_global_load_lds(
      (const __attribute__((address_space(1))) char*)g,
      (__attribute__((address_space(3))) char*)l, 16, 0, 0);
}

// ---------------------------------------------------------------------------
// W_r[(r*COUTP+o), i] = W[o,i] * c_r(P[o,i]); zero rows for o>=COUT, i>=CIN.
// ---------------------------------------------------------------------------
__global__ void build_wr(const float* __restrict__ W, const float* __restrict__ P,
                         __bf16* __restrict__ Wr, int CIN, int CINP, int COUT, int COUTP) {
  int o = blockIdx.x;  // < COUTP
  for (int i = threadIdx.x; i < CINP; i += blockDim.x) {
    bool valid = (o < COUT) && (i < CIN);
    float w = valid ? W[(size_t)o * CIN + i] : 0.f;
    float p = valid ? P[(size_t)o * CIN + i] : 0.f;
    float S = 0.f;
#pragma unroll
    for (int l = 0; l < 25; ++l) {
      float g = ((float)(l - 12) - p) * (1.f / 12.f);
      S += expf(-0.5f * g * g);
    }
    float c = w * expf(-p * p * (1.f / 288.f)) / (S + 1e-7f);
    float pm = p * (1.f / 12.f);
#pragma unroll
    for (int r = 0; r < R_RANK; ++r) {
      Wr[((size_t)r * COUTP + o) * CINP + i] = (__bf16)c;
      c *= pm / (float)(r + 1);
    }
  }
}

// x (B,T,700) f32 -> Xb (T,B,704) bf16 (channel pads zero)
__global__ void fill_xb(const float* __restrict__ x, __bf16* __restrict__ Xb) {
  int tb = blockIdx.x;  // t*128+b
  int t = tb >> 7, b = tb & 127;
  const float* src = x + ((size_t)b * T_LEN + t) * 700;
  __bf16* dst = Xb + (size_t)tb * 704;
  for (int c = threadIdx.x; c < 704; c += 256) dst[c] = (c < 700) ? (__bf16)src[c] : (__bf16)0.f;
}

// ---------------------------------------------------------------------------
// Plain GEMM: Z[n, m] over m=(t,b) rows, n = r*COUTP+o cols; K = CINP.
// 128 x BLK_N tile, 4 waves, 16x16x32 bf16 MFMA, global_load_lds(16B) staging,
// XOR kgroup swizzle. Output bf16 to Z[(r*M + m)*COUTP + o].
// ---------------------------------------------------------------------------
template <int CINP, int BLK_N, int WROWS, int WCOLS, int CO_SH>
__global__ __launch_bounds__(256, 4)
void gemm_rk(const __bf16* __restrict__ A,   // (M, CINP)
             const __bf16* __restrict__ Bm,  // (R*COUTP, CINP)
             __bf16* __restrict__ Z) {       // (R, M, COUTP)
  constexpr int COUTP = 1 << CO_SH;
  constexpr int WM = 128 / WROWS;
  constexpr int WN = BLK_N / WCOLS;
  constexpr int RM = WM / 16;
  constexpr int RN = WN / 16;
  __shared__ __align__(16) __bf16 sA[128 * 32];
  __shared__ __align__(16) __bf16 sB[BLK_N * 32];

  const int tid = threadIdx.x;
  const int w = tid >> 6, lane = tid & 63;
  const int q = lane >> 4, ln = lane & 15;
  const int wrow = w / WCOLS, wcol = w % WCOLS;
  const int srow = lane >> 2;
  const int skg = lane & 3;

  const int t0 = blockIdx.x;
  const int oc = blockIdx.y * BLK_N;
  const __bf16* Abase = A + (size_t)t0 * 128 * CINP;
  const __bf16* Bbase = Bm + (size_t)oc * CINP;

  v4f acc[RM][RN];
#pragma unroll
  for (int a = 0; a < RM; ++a)
#pragma unroll
    for (int b = 0; b < RN; ++b) acc[a][b] = v4f{0.f, 0.f, 0.f, 0.f};

  for (int ic = 0; ic < CINP; ic += 32) {
    for (int j = w; j < 8; j += 4) {
      int m = j * 16 + srow;
      int kg = skg ^ (m & 3);
      gl_lds16(Abase + (size_t)m * CINP + ic + kg * 8, &sA[j * 512]);
    }
    for (int j = w; j < BLK_N / 16; j += 4) {
      int n = j * 16 + srow;
      int kg = skg ^ (n & 3);
      gl_lds16(Bbase + (size_t)n * CINP + ic + kg * 8, &sB[j * 512]);
    }
    __syncthreads();

    v8bf af[RM], bfr[RN];
#pragma unroll
    for (int a = 0; a < RM; ++a) {
      int m = wrow * WM + a * 16 + ln;
      af[a] = *(const v8bf*)&sA[m * 32 + ((q ^ (m & 3)) * 8)];
    }
#pragma unroll
    for (int b = 0; b < RN; ++b) {
      int n = wcol * WN + b * 16 + ln;
      bfr[b] = *(const v8bf*)&sB[n * 32 + ((q ^ (n & 3)) * 8)];
    }
#pragma unroll
    for (int a = 0; a < RM; ++a)
#pragma unroll
      for (int b = 0; b < RN; ++b)
        acc[a][b] = __builtin_amdgcn_mfma_f32_16x16x32_bf16(af[a], bfr[b], acc[a][b], 0, 0, 0);
    __syncthreads();
  }

  // C/D layout: col=lane&15, row=quad*4+reg (m89-verified)
#pragma unroll
  for (int a = 0; a < RM; ++a) {
#pragma unroll
    for (int b = 0; b < RN; ++b) {
      int n = oc + wcol * WN + b * 16 + ln;
      int r = n >> CO_SH, o = n & (COUTP - 1);
#pragma unroll
      for (int rr = 0; rr < 4; ++rr) {
        int m = t0 * 128 + wrow * WM + a * 16 + q * 4 + rr;
        Z[((size_t)r * M_ROWS + m) * COUTP + o] = (__bf16)acc[a][b][rr];
      }
    }
  }
}

// ---------------------------------------------------------------------------
// FIR + rank-sum: Y[t,b,o] = sum_r sum_tau PHI[tau][r] * Z_r[t+tau-24, b, o].
// Thread = (chunk of 25 t, b, o); 49-sample register segment per rank.
// ---------------------------------------------------------------------------
template <int CO_SH>
__global__ __launch_bounds__(256)
void filt_sum(const __bf16* __restrict__ Z, float* __restrict__ Y) {
  constexpr int COUTP = 1 << CO_SH;
  int gid = blockIdx.x * 256 + threadIdx.x;
  int o = gid & (COUTP - 1);
  int b = (gid >> CO_SH) & 127;
  int chunk = gid >> (CO_SH + 7);
  int tc = chunk * 25;

  float y[25];
#pragma unroll
  for (int dt = 0; dt < 25; ++dt) y[dt] = 0.f;

#pragma unroll
  for (int r = 0; r < R_RANK; ++r) {
    const __bf16* Zr = Z + ((size_t)r * M_ROWS + b) * COUTP + o;
    float seg[49];
#pragma unroll
    for (int j = 0; j < 49; ++j) {
      int s = tc - 24 + j;
      seg[j] = (s >= 0) ? (float)Zr[(size_t)s * 128 * COUTP] : 0.f;
    }
#pragma unroll
    for (int dt = 0; dt < 25; ++dt)
#pragma unroll
      for (int tau = 0; tau < 25; ++tau)
        y[dt] = fmaf(PHI.v[tau][r], seg[dt + tau], y[dt]);
  }
#pragma unroll
  for (int dt = 0; dt < 25; ++dt)
    Y[((size_t)(tc + dt) * 128 + b) * COUTP + o] = y[dt];
}

// BN stats: per-channel sum/sumsq over 12800 rows, C=256.
__global__ void bn_stats(const float* __restrict__ h, float* __restrict__ stats) {
  int c = threadIdx.x;
  size_t r0 = (size_t)blockIdx.x * 128;
  float s = 0.f, ss = 0.f;
  for (int r = 0; r < 128; ++r) {
    float v = h[(r0 + r) * 256 + c];
    s += v; ss += v * v;
  }
  atomicAdd(&stats[c], s);
  atomicAdd(&stats[256 + c], ss);
}

__global__ void bn_apply_relu(const float* __restrict__ h, const float* __restrict__ stats,
                              const float* __restrict__ gamma, const float* __restrict__ beta,
                              __bf16* __restrict__ hb) {
  int c = threadIdx.x;
  size_t row = blockIdx.x;
  float mean = stats[c] * (1.f / 12800.f);
  float var = stats[256 + c] * (1.f / 12800.f) - mean * mean;
  float inv = rsqrtf(var + 1e-5f) * gamma[c];
  float v = (h[row * 256 + c] - mean) * inv + beta[c];
  hb[row * 256 + c] = (__bf16)fmaxf(v, 0.f);
}

// softmax over 20 logits (stride-32 rows), sum over T via atomics
__global__ void softmax_sum(const float* __restrict__ y3, float* __restrict__ out) {
  int b = threadIdx.x;  // 128
  int t = blockIdx.x;   // 100
  const float* r = y3 + ((size_t)t * B_SZ + b) * 32;
  float v[20], m = -1e30f;
#pragma unroll
  for (int o = 0; o < 20; ++o) { v[o] = r[o]; m = fmaxf(m, v[o]); }
  float s = 0.f;
#pragma unroll
  for (int o = 0; o < 20; ++o) { v[o] = expf(v[o] - m); s += v[o]; }
  float inv = 1.f / s;
#pragma unroll
  for (int o = 0; o < 20; ++o) atomicAdd(&out[b * 20 + o], v[o] * inv);
}

// ---------------------------------------------------------------------------

extern "C" void kernel_launch(void* const* d_in, const int* in_sizes, int n_in,
                              void* d_out, int out_size, void* d_ws, size_t ws_size,
                              hipStream_t stream) {
  const float* x  = (const float*)d_in[0];
  const float* W1 = (const float*)d_in[1];
  const float* P1 = (const float*)d_in[2];
  const float* W2 = (const float*)d_in[3];
  const float* P2 = (const float*)d_in[4];
  const float* W3 = (const float*)d_in[5];
  const float* P3 = (const float*)d_in[6];
  const float* g1 = (const float*)d_in[7];
  const float* b1 = (const float*)d_in[8];
  const float* g2 = (const float*)d_in[9];
  const float* b2 = (const float*)d_in[10];
  float* out = (float*)d_out;

  constexpr size_t XB_B  = (size_t)M_ROWS * 704 * 2;          // 18,022,400
  constexpr size_t Z_B   = (size_t)R_RANK * M_ROWS * 256 * 2; // 39,321,600
  constexpr size_t Y_B   = (size_t)M_ROWS * 256 * 4;          // 13,107,200
  constexpr size_t H_B   = (size_t)M_ROWS * 256 * 2;          //  6,553,600
  constexpr size_t W1_B  = (size_t)R_RANK * 256 * 704 * 2;    //  2,162,688
  constexpr size_t W2_B  = (size_t)R_RANK * 256 * 256 * 2;    //    786,432
  constexpr size_t W3_B  = (size_t)R_RANK * 32 * 256 * 2;     //     98,304
  constexpr size_t ST_B  = 4096;
  constexpr size_t TOTAL = XB_B + Z_B + Y_B + H_B + W1_B + W2_B + W3_B + ST_B; // ~80.1 MB
  if (ws_size < TOTAL) return;

  char* ws = (char*)d_ws;
  __bf16* Xb   = (__bf16*)(ws);
  __bf16* Zb   = (__bf16*)(ws + XB_B);                 // Z1 / Z2 / Z3 (sequential reuse)
  float*  Yf   = (float*)(ws + XB_B + Z_B);            // y1 / y2 / y3 (sequential reuse)
  __bf16* Hb   = (__bf16*)(ws + XB_B + Z_B + Y_B);     // h1 / h2 (sequential reuse)
  __bf16* Wr1  = (__bf16*)(ws + XB_B + Z_B + Y_B + H_B);
  __bf16* Wr2  = (__bf16*)(ws + XB_B + Z_B + Y_B + H_B + W1_B);
  __bf16* Wr3  = (__bf16*)(ws + XB_B + Z_B + Y_B + H_B + W1_B + W2_B);
  float*  stats1 = (float*)(ws + XB_B + Z_B + Y_B + H_B + W1_B + W2_B + W3_B);
  float*  stats2 = stats1 + 512;

  hipMemsetAsync(stats1, 0, ST_B, stream);
  hipMemsetAsync(out, 0, (size_t)out_size * 4, stream);

  build_wr<<<dim3(256), 256, 0, stream>>>(W1, P1, Wr1, 700, 704, 256, 256);
  build_wr<<<dim3(256), 256, 0, stream>>>(W2, P2, Wr2, 256, 256, 256, 256);
  build_wr<<<dim3(32),  256, 0, stream>>>(W3, P3, Wr3, 256, 256, 20, 32);
  fill_xb<<<dim3(12800), 256, 0, stream>>>(x, Xb);

  // layer 1: GEMM (12800 x 1536 x 704) -> FIR -> BN+ReLU
  gemm_rk<704, 128, 2, 2, 8><<<dim3(100, 12), 256, 0, stream>>>(Xb, Wr1, Zb);
  filt_sum<8><<<dim3(512), 256, 0, stream>>>(Zb, Yf);
  bn_stats<<<dim3(100), 256, 0, stream>>>(Yf, stats1);
  bn_apply_relu<<<dim3(12800), 256, 0, stream>>>(Yf, stats1, g1, b1, Hb);

  // layer 2: GEMM (12800 x 1536 x 256)
  gemm_rk<256, 128, 2, 2, 8><<<dim3(100, 12), 256, 0, stream>>>(Hb, Wr2, Zb);
  filt_sum<8><<<dim3(512), 256, 0, stream>>>(Zb, Yf);
  bn_stats<<<dim3(100), 256, 0, stream>>>(Yf, stats2);
  bn_apply_relu<<<dim3(12800), 256, 0, stream>>>(Yf, stats2, g2, b2, Hb);

  // layer 3: GEMM (12800 x 192 x 256), COUTP=32
  gemm_rk<256, 64, 2, 2, 5><<<dim3(100, 3), 256, 0, stream>>>(Hb, Wr3, Zb);
  filt_sum<5><<<dim3(64), 256, 0, stream>>>(Zb, Yf);
  softmax_sum<<<dim3(100), 128, 0, stream>>>(Yf, out);
}

// Round 3
// 338.801 us; speedup vs baseline: 1.7865x; 1.7865x over previous
//
#include <hip/hip_runtime.h>
#include <stdint.h>

// ---------------------------------------------------------------------------
// d128snn_delays, round 3: low-rank DCLS (rank-6 Taylor) + FIR-as-GEMM.
//   Layer: Z_r = X @ W_r^T  (gemm_rk, MFMA), then
//          Y[t,n] = sum_{k=(r,s)} Mfir[t,k] * Z[k,n]  (fir_gemm, MFMA),
//   with Mfir[t, r*100+s] = phi_r(s-t+24) banded (112x608 padded).
//   fir_gemm fuses BN sum/sumsq (atomics) and writes bf16 Y.
// ---------------------------------------------------------------------------

#define T_LEN 100
#define B_SZ  128
#define M_ROWS 12800
#define R_RANK 6

typedef __bf16 v8bf __attribute__((ext_vector_type(8)));
typedef float  v4f  __attribute__((ext_vector_type(4)));
typedef unsigned int uint32;
typedef unsigned short ushort16;

// PHI[tau][r] = exp(-l'^2/288) * (l'/12)^r, l' = tau-12
struct PhiT { float v[25][R_RANK]; };
constexpr double cexp_(double x) {
  double s = 1.0, t = 1.0;
  for (int n = 1; n < 30; ++n) { t = t * x / n; s += t; }
  return s;
}
constexpr PhiT make_phi() {
  PhiT P{};
  for (int tau = 0; tau < 25; ++tau) {
    double lp = (tau - 12) / 12.0;
    double g = cexp_(-0.5 * lp * lp);
    double m = 1.0;
    for (int r = 0; r < R_RANK; ++r) { P.v[tau][r] = (float)(g * m); m *= lp; }
  }
  return P;
}
constexpr PhiT PHI = make_phi();

__device__ __forceinline__ void gl_lds16(const void* g, void* l) {
  __builtin_amdgcn_global_load_lds(
      (const __attribute__((address_space(1))) char*)g,
      (__attribute__((address_space(3))) char*)l, 16, 0, 0);
}

// ---------------------------------------------------------------------------
// W_r[(r*COUTP+o), i] = W[o,i] * c_r(P[o,i])
// ---------------------------------------------------------------------------
__global__ void build_wr(const float* __restrict__ W, const float* __restrict__ P,
                         __bf16* __restrict__ Wr, int CIN, int CINP, int COUT, int COUTP) {
  int o = blockIdx.x;
  for (int i = threadIdx.x; i < CINP; i += blockDim.x) {
    bool valid = (o < COUT) && (i < CIN);
    float w = valid ? W[(size_t)o * CIN + i] : 0.f;
    float p = valid ? P[(size_t)o * CIN + i] : 0.f;
    float S = 0.f;
#pragma unroll
    for (int l = 0; l < 25; ++l) {
      float g = ((float)(l - 12) - p) * (1.f / 12.f);
      S += expf(-0.5f * g * g);
    }
    float c = w * expf(-p * p * (1.f / 288.f)) / (S + 1e-7f);
    float pm = p * (1.f / 12.f);
#pragma unroll
    for (int r = 0; r < R_RANK; ++r) {
      Wr[((size_t)r * COUTP + o) * CINP + i] = (__bf16)c;
      c *= pm / (float)(r + 1);
    }
  }
}

// Afir (112 x 608) bf16: Afir[t][r*100+s] = PHI[s-t+24][r] in-band else 0
__global__ void build_afir(__bf16* __restrict__ Af) {
  int idx = blockIdx.x * 256 + threadIdx.x;
  if (idx >= 112 * 608) return;
  int t = idx / 608, k = idx - t * 608;
  float v = 0.f;
  if (t < 100 && k < 600) {
    int r = k / 100, s = k - r * 100;
    int tau = s - t + 24;
    if (tau >= 0 && tau < 25) v = PHI.v[tau][r];
  }
  Af[idx] = (__bf16)v;
}

// x (B,T,700) f32 -> Xb (T,B,704) bf16
__global__ void fill_xb(const float* __restrict__ x, __bf16* __restrict__ Xb) {
  int tb = blockIdx.x;
  int t = tb >> 7, b = tb & 127;
  const float* src = x + ((size_t)b * T_LEN + t) * 700;
  __bf16* dst = Xb + (size_t)tb * 704;
  for (int c = threadIdx.x; c < 704; c += 256) dst[c] = (c < 700) ? (__bf16)src[c] : (__bf16)0.f;
}

// ---------------------------------------------------------------------------
// Main GEMM (unchanged from R2): Z[k=(r,t)][n=(b,o)] = X @ Wr^T
// ---------------------------------------------------------------------------
template <int CINP, int BLK_N, int WROWS, int WCOLS, int CO_SH>
__global__ __launch_bounds__(256, 4)
void gemm_rk(const __bf16* __restrict__ A, const __bf16* __restrict__ Bm,
             __bf16* __restrict__ Z) {
  constexpr int COUTP = 1 << CO_SH;
  constexpr int WM = 128 / WROWS;
  constexpr int WN = BLK_N / WCOLS;
  constexpr int RM = WM / 16;
  constexpr int RN = WN / 16;
  __shared__ __align__(16) __bf16 sA[128 * 32];
  __shared__ __align__(16) __bf16 sB[BLK_N * 32];

  const int tid = threadIdx.x;
  const int w = tid >> 6, lane = tid & 63;
  const int q = lane >> 4, ln = lane & 15;
  const int wrow = w / WCOLS, wcol = w % WCOLS;
  const int srow = lane >> 2;
  const int skg = lane & 3;

  const int t0 = blockIdx.x;
  const int oc = blockIdx.y * BLK_N;
  const __bf16* Abase = A + (size_t)t0 * 128 * CINP;
  const __bf16* Bbase = Bm + (size_t)oc * CINP;

  v4f acc[RM][RN];
#pragma unroll
  for (int a = 0; a < RM; ++a)
#pragma unroll
    for (int b = 0; b < RN; ++b) acc[a][b] = v4f{0.f, 0.f, 0.f, 0.f};

  for (int ic = 0; ic < CINP; ic += 32) {
    for (int j = w; j < 8; j += 4) {
      int m = j * 16 + srow;
      int kg = skg ^ (m & 3);
      gl_lds16(Abase + (size_t)m * CINP + ic + kg * 8, &sA[j * 512]);
    }
    for (int j = w; j < BLK_N / 16; j += 4) {
      int n = j * 16 + srow;
      int kg = skg ^ (n & 3);
      gl_lds16(Bbase + (size_t)n * CINP + ic + kg * 8, &sB[j * 512]);
    }
    __syncthreads();

    v8bf af[RM], bfr[RN];
#pragma unroll
    for (int a = 0; a < RM; ++a) {
      int m = wrow * WM + a * 16 + ln;
      af[a] = *(const v8bf*)&sA[m * 32 + ((q ^ (m & 3)) * 8)];
    }
#pragma unroll
    for (int b = 0; b < RN; ++b) {
      int n = wcol * WN + b * 16 + ln;
      bfr[b] = *(const v8bf*)&sB[n * 32 + ((q ^ (n & 3)) * 8)];
    }
#pragma unroll
    for (int a = 0; a < RM; ++a)
#pragma unroll
      for (int b = 0; b < RN; ++b)
        acc[a][b] = __builtin_amdgcn_mfma_f32_16x16x32_bf16(af[a], bfr[b], acc[a][b], 0, 0, 0);
    __syncthreads();
  }

#pragma unroll
  for (int a = 0; a < RM; ++a) {
#pragma unroll
    for (int b = 0; b < RN; ++b) {
      int n = oc + wcol * WN + b * 16 + ln;
      int r = n >> CO_SH, o = n & (COUTP - 1);
#pragma unroll
      for (int rr = 0; rr < 4; ++rr) {
        int m = t0 * 128 + wrow * WM + a * 16 + q * 4 + rr;
        Z[((size_t)r * M_ROWS + m) * COUTP + o] = (__bf16)acc[a][b][rr];
      }
    }
  }
}

// ---------------------------------------------------------------------------
// FIR GEMM: Y(112x N-tile 128) = Afir(112x608) @ Z(608xN).
// B-tile transposed in LDS: thread loads 2 k-rows x 8n (dwordx4), packs
// k-pairs into b32 writes at [n][stride 38] (4-way conflicts only); B-frag
// read = 4x b32. A staged via global_load_lds + XOR swizzle.
// Fuses BN sum/sumsq (STATS) and bf16 output (BF16OUT).
// ---------------------------------------------------------------------------
template <int COUTP, bool STATS, bool BF16OUT>
__global__ __launch_bounds__(256, 2)
void fir_gemm(const __bf16* __restrict__ Af, const __bf16* __restrict__ Z,
              void* __restrict__ Yout, float* __restrict__ stats, int N) {
  constexpr int SBS = 38;  // elems; 19 dwords (odd) -> n-spread reads
  __shared__ __align__(16) __bf16 sA[7 * 512];
  __shared__ __align__(16) __bf16 sB[128 * SBS];
  uint32* sBu = (uint32*)sB;

  const int tid = threadIdx.x;
  const int w = tid >> 6, lane = tid & 63;
  const int q = lane >> 4, ln = lane & 15;
  const int srow = lane >> 2, skg = lane & 3;
  const int kp = tid >> 4;    // k-pair 0..15
  const int noct = tid & 15;  // n-octet 0..15
  const int nb = blockIdx.x * 128;

  v4f acc[7][2];
#pragma unroll
  for (int a = 0; a < 7; ++a)
#pragma unroll
    for (int b = 0; b < 2; ++b) acc[a][b] = v4f{0.f, 0.f, 0.f, 0.f};

  for (int kc = 0; kc < 608; kc += 32) {
    // stage A (112 x 32)
    for (int j = w; j < 7; j += 4) {
      int mr = j * 16 + srow;
      int kg = skg ^ (mr & 3);
      gl_lds16(Af + (size_t)mr * 608 + kc + kg * 8, &sA[j * 512]);
    }
    // stage B transposed: rows kc+2kp, kc+2kp+1; cols nb+noct*8..+7
    const __bf16* zp = Z + (size_t)(kc + kp * 2) * N + nb + noct * 8;
    uint4 r0 = *(const uint4*)zp;
    uint4 r1 = *(const uint4*)(zp + N);
    const ushort16* p0 = (const ushort16*)&r0;
    const ushort16* p1 = (const ushort16*)&r1;
#pragma unroll
    for (int j = 0; j < 8; ++j) {
      uint32 val = (uint32)p0[j] | ((uint32)p1[j] << 16);
      sBu[(size_t)(noct * 8 + j) * 19 + kp] = val;
    }
    __syncthreads();

    v8bf af[7];
#pragma unroll
    for (int a = 0; a < 7; ++a) {
      int m = a * 16 + ln;
      af[a] = *(const v8bf*)&sA[m * 32 + ((q ^ (m & 3)) * 8)];
    }
    v8bf bfr[2];
#pragma unroll
    for (int bt = 0; bt < 2; ++bt) {
      int nl = w * 32 + bt * 16 + ln;
      int base = nl * 19 + q * 4;
      uint32 u0 = sBu[base], u1 = sBu[base + 1], u2 = sBu[base + 2], u3 = sBu[base + 3];
      uint32 tmp[4] = {u0, u1, u2, u3};
      bfr[bt] = *(const v8bf*)tmp;
    }
#pragma unroll
    for (int a = 0; a < 7; ++a)
#pragma unroll
      for (int bt = 0; bt < 2; ++bt)
        acc[a][bt] = __builtin_amdgcn_mfma_f32_16x16x32_bf16(af[a], bfr[bt], acc[a][bt], 0, 0, 0);
    __syncthreads();
  }

  // epilogue: rows t = a*16+q*4+rr (<100), col ng
#pragma unroll
  for (int bt = 0; bt < 2; ++bt) {
    int ng = nb + w * 32 + bt * 16 + ln;
    float s = 0.f, ss = 0.f;
#pragma unroll
    for (int a = 0; a < 7; ++a) {
#pragma unroll
      for (int rr = 0; rr < 4; ++rr) {
        int t = a * 16 + q * 4 + rr;
        float v = acc[a][bt][rr];
        if (t < 100) {
          if (BF16OUT) ((__bf16*)Yout)[(size_t)t * N + ng] = (__bf16)v;
          else         ((float*)Yout)[(size_t)t * N + ng] = v;
          s += v; ss += v * v;
        }
      }
    }
    if (STATS) {
      s += __shfl_xor(s, 16); ss += __shfl_xor(ss, 16);
      s += __shfl_xor(s, 32); ss += __shfl_xor(ss, 32);
      if (q == 0) {
        int o = ng & (COUTP - 1);
        atomicAdd(&stats[o], s);
        atomicAdd(&stats[COUTP + o], ss);
      }
    }
  }
}

// normalize + relu + bf16 (input now bf16)
__global__ void bn_apply_relu(const __bf16* __restrict__ h, const float* __restrict__ stats,
                              const float* __restrict__ gamma, const float* __restrict__ beta,
                              __bf16* __restrict__ hb) {
  int c = threadIdx.x;
  size_t row = blockIdx.x;
  float mean = stats[c] * (1.f / 12800.f);
  float var = stats[256 + c] * (1.f / 12800.f) - mean * mean;
  float inv = rsqrtf(var + 1e-5f) * gamma[c];
  float v = ((float)h[row * 256 + c] - mean) * inv + beta[c];
  hb[row * 256 + c] = (__bf16)fmaxf(v, 0.f);
}

__global__ void softmax_sum(const float* __restrict__ y3, float* __restrict__ out) {
  int b = threadIdx.x;
  int t = blockIdx.x;
  const float* r = y3 + ((size_t)t * B_SZ + b) * 32;
  float v[20], m = -1e30f;
#pragma unroll
  for (int o = 0; o < 20; ++o) { v[o] = r[o]; m = fmaxf(m, v[o]); }
  float s = 0.f;
#pragma unroll
  for (int o = 0; o < 20; ++o) { v[o] = expf(v[o] - m); s += v[o]; }
  float inv = 1.f / s;
#pragma unroll
  for (int o = 0; o < 20; ++o) atomicAdd(&out[b * 20 + o], v[o] * inv);
}

// ---------------------------------------------------------------------------

extern "C" void kernel_launch(void* const* d_in, const int* in_sizes, int n_in,
                              void* d_out, int out_size, void* d_ws, size_t ws_size,
                              hipStream_t stream) {
  const float* x  = (const float*)d_in[0];
  const float* W1 = (const float*)d_in[1];
  const float* P1 = (const float*)d_in[2];
  const float* W2 = (const float*)d_in[3];
  const float* P2 = (const float*)d_in[4];
  const float* W3 = (const float*)d_in[5];
  const float* P3 = (const float*)d_in[6];
  const float* g1 = (const float*)d_in[7];
  const float* b1 = (const float*)d_in[8];
  const float* g2 = (const float*)d_in[9];
  const float* b2 = (const float*)d_in[10];
  float* out = (float*)d_out;

  constexpr size_t XB_B  = (size_t)M_ROWS * 704 * 2;       // 18,022,400
  constexpr size_t Z_B   = (size_t)608 * 32768 * 2;        // 39,845,888 (608 rows incl pad)
  constexpr size_t Y12_B = (size_t)M_ROWS * 256 * 2;       //  6,553,600 bf16
  constexpr size_t Y3_B  = (size_t)M_ROWS * 32 * 4;        //  1,638,400 f32
  constexpr size_t H_B   = (size_t)M_ROWS * 256 * 2;       //  6,553,600
  constexpr size_t W1_B  = (size_t)R_RANK * 256 * 704 * 2; //  2,162,688
  constexpr size_t W2_B  = (size_t)R_RANK * 256 * 256 * 2; //    786,432
  constexpr size_t W3_B  = (size_t)R_RANK * 32 * 256 * 2;  //     98,304
  constexpr size_t AF_B  = (size_t)112 * 608 * 2;          //    136,192
  constexpr size_t ST_B  = 4096;
  constexpr size_t TOTAL = XB_B + Z_B + Y12_B + Y3_B + H_B + W1_B + W2_B + W3_B + AF_B + ST_B; // ~75.8 MB
  if (ws_size < TOTAL) return;

  char* ws = (char*)d_ws;
  size_t off = 0;
  __bf16* Xb   = (__bf16*)(ws + off); off += XB_B;
  __bf16* Zb   = (__bf16*)(ws + off); off += Z_B;
  __bf16* Yb   = (__bf16*)(ws + off); off += Y12_B;
  float*  Y3f  = (float*)(ws + off);  off += Y3_B;
  __bf16* Hb   = (__bf16*)(ws + off); off += H_B;
  __bf16* Wr1  = (__bf16*)(ws + off); off += W1_B;
  __bf16* Wr2  = (__bf16*)(ws + off); off += W2_B;
  __bf16* Wr3  = (__bf16*)(ws + off); off += W3_B;
  __bf16* Afir = (__bf16*)(ws + off); off += AF_B;
  float*  stats1 = (float*)(ws + off);
  float*  stats2 = stats1 + 512;

  hipMemsetAsync(stats1, 0, ST_B, stream);
  hipMemsetAsync(out, 0, (size_t)out_size * 4, stream);
  // zero K-pad rows 600..607 for the N=32768 layout (never written by gemm_rk)
  hipMemsetAsync((char*)Zb + (size_t)600 * 32768 * 2, 0, (size_t)8 * 32768 * 2, stream);

  build_wr<<<dim3(256), 256, 0, stream>>>(W1, P1, Wr1, 700, 704, 256, 256);
  build_wr<<<dim3(256), 256, 0, stream>>>(W2, P2, Wr2, 256, 256, 256, 256);
  build_wr<<<dim3(32),  256, 0, stream>>>(W3, P3, Wr3, 256, 256, 20, 32);
  build_afir<<<dim3(267), 256, 0, stream>>>(Afir);
  fill_xb<<<dim3(12800), 256, 0, stream>>>(x, Xb);

  // layer 1
  gemm_rk<704, 128, 2, 2, 8><<<dim3(100, 12), 256, 0, stream>>>(Xb, Wr1, Zb);
  fir_gemm<256, true, true><<<dim3(256), 256, 0, stream>>>(Afir, Zb, Yb, stats1, 32768);
  bn_apply_relu<<<dim3(12800), 256, 0, stream>>>(Yb, stats1, g1, b1, Hb);

  // layer 2
  gemm_rk<256, 128, 2, 2, 8><<<dim3(100, 12), 256, 0, stream>>>(Hb, Wr2, Zb);
  fir_gemm<256, true, true><<<dim3(256), 256, 0, stream>>>(Afir, Zb, Yb, stats2, 32768);
  bn_apply_relu<<<dim3(12800), 256, 0, stream>>>(Yb, stats2, g2, b2, Hb);

  // layer 3 (COUTP=32, N=4096)
  gemm_rk<256, 64, 2, 2, 5><<<dim3(100, 3), 256, 0, stream>>>(Hb, Wr3, Zb);
  hipMemsetAsync((char*)Zb + (size_t)600 * 4096 * 2, 0, (size_t)8 * 4096 * 2, stream);
  fir_gemm<32, false, false><<<dim3(32), 256, 0, stream>>>(Afir, Zb, Y3f, nullptr, 4096);

  softmax_sum<<<dim3(100), 128, 0, stream>>>(Y3f, out);
}

// Round 4
// 254.165 us; speedup vs baseline: 2.3814x; 1.3330x over previous
//
#include <hip/hip_runtime.h>
#include <stdint.h>

// ---------------------------------------------------------------------------
// d128snn_delays, round 4: low-rank DCLS (rank-6 Taylor) + FIR-as-GEMM.
//   Layer: Z_r = X @ W_r^T (gemm_rk, MFMA), Y = Afir @ Z (fir_gemm, MFMA,
//   fused BN stats), bn_apply (vectorized), block-reduced softmax.
// R4: single fused setup kernel (no memsets: Afir zero-cols absorb Z pad
// garbage), atomic-free softmax, fir_gemm at N-tile 64 for 2+ blocks/CU.
// ---------------------------------------------------------------------------

#define T_LEN 100
#define B_SZ  128
#define M_ROWS 12800
#define R_RANK 6

typedef __bf16 v8bf __attribute__((ext_vector_type(8)));
typedef float  v4f  __attribute__((ext_vector_type(4)));
typedef unsigned int uint32;
typedef unsigned short ushort_t;

// PHI[tau][r] = exp(-l'^2/288) * (l'/12)^r, l' = tau-12
struct PhiT { float v[25][R_RANK]; };
constexpr double cexp_(double x) {
  double s = 1.0, t = 1.0;
  for (int n = 1; n < 30; ++n) { t = t * x / n; s += t; }
  return s;
}
constexpr PhiT make_phi() {
  PhiT P{};
  for (int tau = 0; tau < 25; ++tau) {
    double lp = (tau - 12) / 12.0;
    double g = cexp_(-0.5 * lp * lp);
    double m = 1.0;
    for (int r = 0; r < R_RANK; ++r) { P.v[tau][r] = (float)(g * m); m *= lp; }
  }
  return P;
}
constexpr PhiT PHI = make_phi();

__device__ __forceinline__ void gl_lds16(const void* g, void* l) {
  __builtin_amdgcn_global_load_lds(
      (const __attribute__((address_space(1))) char*)g,
      (__attribute__((address_space(3))) char*)l, 16, 0, 0);
}

// ---------------------------------------------------------------------------
// Fused setup: build_wr x3 + build_afir + fill_xb + stats zero, one dispatch.
// ---------------------------------------------------------------------------
__device__ __forceinline__ void build_wr_body(
    const float* __restrict__ W, const float* __restrict__ P,
    __bf16* __restrict__ Wr, int CIN, int CINP, int COUT, int COUTP, int o) {
  for (int i = threadIdx.x; i < CINP; i += blockDim.x) {
    bool valid = (o < COUT) && (i < CIN);
    float w = valid ? W[(size_t)o * CIN + i] : 0.f;
    float p = valid ? P[(size_t)o * CIN + i] : 0.f;
    float S = 0.f;
#pragma unroll
    for (int l = 0; l < 25; ++l) {
      float g = ((float)(l - 12) - p) * (1.f / 12.f);
      S += expf(-0.5f * g * g);
    }
    float c = w * expf(-p * p * (1.f / 288.f)) / (S + 1e-7f);
    float pm = p * (1.f / 12.f);
#pragma unroll
    for (int r = 0; r < R_RANK; ++r) {
      Wr[((size_t)r * COUTP + o) * CINP + i] = (__bf16)c;
      c *= pm / (float)(r + 1);
    }
  }
}

__global__ void setup_all(const float* __restrict__ x,
                          const float* __restrict__ W1, const float* __restrict__ P1,
                          const float* __restrict__ W2, const float* __restrict__ P2,
                          const float* __restrict__ W3, const float* __restrict__ P3,
                          __bf16* __restrict__ Xb, __bf16* __restrict__ Wr1,
                          __bf16* __restrict__ Wr2, __bf16* __restrict__ Wr3,
                          __bf16* __restrict__ Af, float* __restrict__ stats) {
  int blk = blockIdx.x;
  if (blk < 256) { build_wr_body(W1, P1, Wr1, 700, 704, 256, 256, blk); return; }
  blk -= 256;
  if (blk < 256) { build_wr_body(W2, P2, Wr2, 256, 256, 256, 256, blk); return; }
  blk -= 256;
  if (blk < 32) { build_wr_body(W3, P3, Wr3, 256, 256, 20, 32, blk); return; }
  blk -= 32;
  if (blk < 267) {  // Afir (112 x 608): [t][r*100+s] = PHI[s-t+24][r], else 0
    int idx = blk * 256 + threadIdx.x;
    if (idx < 112 * 608) {
      int t = idx / 608, k = idx - t * 608;
      float v = 0.f;
      if (t < 100 && k < 600) {
        int r = k / 100, s = k - r * 100;
        int tau = s - t + 24;
        if (tau >= 0 && tau < 25) v = PHI.v[tau][r];
      }
      Af[idx] = (__bf16)v;
    }
    return;
  }
  blk -= 267;
  if (blk < 12800) {  // x (B,T,700) f32 -> Xb (T,B,704) bf16
    int t = blk >> 7, b = blk & 127;
    const float* src = x + ((size_t)b * T_LEN + t) * 700;
    __bf16* dst = Xb + (size_t)blk * 704;
    for (int c = threadIdx.x; c < 704; c += 256) dst[c] = (c < 700) ? (__bf16)src[c] : (__bf16)0.f;
    return;
  }
  blk -= 12800;
  if (blk == 0) {  // zero BN-stat accumulators (1024 floats)
    for (int i = threadIdx.x; i < 1024; i += 256) stats[i] = 0.f;
  }
}

// ---------------------------------------------------------------------------
// Main GEMM: Z[k=(r,t)][n=(b,o)] = X @ Wr^T   (m97 structure, unchanged)
// ---------------------------------------------------------------------------
template <int CINP, int BLK_N, int WROWS, int WCOLS, int CO_SH>
__global__ __launch_bounds__(256, 4)
void gemm_rk(const __bf16* __restrict__ A, const __bf16* __restrict__ Bm,
             __bf16* __restrict__ Z) {
  constexpr int COUTP = 1 << CO_SH;
  constexpr int WM = 128 / WROWS;
  constexpr int WN = BLK_N / WCOLS;
  constexpr int RM = WM / 16;
  constexpr int RN = WN / 16;
  __shared__ __align__(16) __bf16 sA[128 * 32];
  __shared__ __align__(16) __bf16 sB[BLK_N * 32];

  const int tid = threadIdx.x;
  const int w = tid >> 6, lane = tid & 63;
  const int q = lane >> 4, ln = lane & 15;
  const int wrow = w / WCOLS, wcol = w % WCOLS;
  const int srow = lane >> 2;
  const int skg = lane & 3;

  const int t0 = blockIdx.x;
  const int oc = blockIdx.y * BLK_N;
  const __bf16* Abase = A + (size_t)t0 * 128 * CINP;
  const __bf16* Bbase = Bm + (size_t)oc * CINP;

  v4f acc[RM][RN];
#pragma unroll
  for (int a = 0; a < RM; ++a)
#pragma unroll
    for (int b = 0; b < RN; ++b) acc[a][b] = v4f{0.f, 0.f, 0.f, 0.f};

  for (int ic = 0; ic < CINP; ic += 32) {
    for (int j = w; j < 8; j += 4) {
      int m = j * 16 + srow;
      int kg = skg ^ (m & 3);
      gl_lds16(Abase + (size_t)m * CINP + ic + kg * 8, &sA[j * 512]);
    }
    for (int j = w; j < BLK_N / 16; j += 4) {
      int n = j * 16 + srow;
      int kg = skg ^ (n & 3);
      gl_lds16(Bbase + (size_t)n * CINP + ic + kg * 8, &sB[j * 512]);
    }
    __syncthreads();

    v8bf af[RM], bfr[RN];
#pragma unroll
    for (int a = 0; a < RM; ++a) {
      int m = wrow * WM + a * 16 + ln;
      af[a] = *(const v8bf*)&sA[m * 32 + ((q ^ (m & 3)) * 8)];
    }
#pragma unroll
    for (int b = 0; b < RN; ++b) {
      int n = wcol * WN + b * 16 + ln;
      bfr[b] = *(const v8bf*)&sB[n * 32 + ((q ^ (n & 3)) * 8)];
    }
#pragma unroll
    for (int a = 0; a < RM; ++a)
#pragma unroll
      for (int b = 0; b < RN; ++b)
        acc[a][b] = __builtin_amdgcn_mfma_f32_16x16x32_bf16(af[a], bfr[b], acc[a][b], 0, 0, 0);
    __syncthreads();
  }

#pragma unroll
  for (int a = 0; a < RM; ++a) {
#pragma unroll
    for (int b = 0; b < RN; ++b) {
      int n = oc + wcol * WN + b * 16 + ln;
      int r = n >> CO_SH, o = n & (COUTP - 1);
#pragma unroll
      for (int rr = 0; rr < 4; ++rr) {
        int m = t0 * 128 + wrow * WM + a * 16 + q * 4 + rr;
        Z[((size_t)r * M_ROWS + m) * COUTP + o] = (__bf16)acc[a][b][rr];
      }
    }
  }
}

// ---------------------------------------------------------------------------
// FIR GEMM, N-tile 64: Y(112 x 64) = Afir(112x608) @ Z(608 x N-slice).
// B transposed in LDS (k-pair packed b32, [n][19-dword stride], 2 lanes/bank).
// Fuses BN sum/sumsq; K-pad rows 600-607 are annihilated by Afir zeros.
// ---------------------------------------------------------------------------
template <int COUTP, bool STATS, bool BF16OUT>
__global__ __launch_bounds__(256, 4)
void fir_gemm(const __bf16* __restrict__ Af, const __bf16* __restrict__ Z,
              void* __restrict__ Yout, float* __restrict__ stats, int N) {
  __shared__ __align__(16) __bf16 sA[7 * 512];
  __shared__ __align__(16) uint32 sBu[64 * 19];

  const int tid = threadIdx.x;
  const int w = tid >> 6, lane = tid & 63;
  const int q = lane >> 4, ln = lane & 15;
  const int srow = lane >> 2, skg = lane & 3;
  const int kp = tid >> 3;   // k-pair 0..15 (tid < 128)
  const int noct = tid & 7;  // n-octet 0..7
  const int nb = blockIdx.x * 64;

  v4f acc[7];
#pragma unroll
  for (int a = 0; a < 7; ++a) acc[a] = v4f{0.f, 0.f, 0.f, 0.f};

  for (int kc = 0; kc < 608; kc += 32) {
    // stage A (112 x 32) via global_load_lds
    for (int j = w; j < 7; j += 4) {
      int mr = j * 16 + srow;
      int kg = skg ^ (mr & 3);
      gl_lds16(Af + (size_t)mr * 608 + kc + kg * 8, &sA[j * 512]);
    }
    // stage B transposed: threads 0..127, rows kc+2kp..+1, cols nb+noct*8..+7
    if (tid < 128) {
      const __bf16* zp = Z + (size_t)(kc + kp * 2) * N + nb + noct * 8;
      uint4 r0 = *(const uint4*)zp;
      uint4 r1 = *(const uint4*)(zp + N);
      const ushort_t* p0 = (const ushort_t*)&r0;
      const ushort_t* p1 = (const ushort_t*)&r1;
#pragma unroll
      for (int j = 0; j < 8; ++j) {
        uint32 val = (uint32)p0[j] | ((uint32)p1[j] << 16);
        sBu[(noct * 8 + j) * 19 + kp] = val;
      }
    }
    __syncthreads();

    v8bf af[7];
#pragma unroll
    for (int a = 0; a < 7; ++a) {
      int m = a * 16 + ln;
      af[a] = *(const v8bf*)&sA[m * 32 + ((q ^ (m & 3)) * 8)];
    }
    int base = (w * 16 + ln) * 19 + q * 4;
    uint32 tmp[4] = {sBu[base], sBu[base + 1], sBu[base + 2], sBu[base + 3]};
    v8bf bfr = *(const v8bf*)tmp;
#pragma unroll
    for (int a = 0; a < 7; ++a)
      acc[a] = __builtin_amdgcn_mfma_f32_16x16x32_bf16(af[a], bfr, acc[a], 0, 0, 0);
    __syncthreads();
  }

  // epilogue: rows t = a*16+q*4+rr (<100), col ng = nb + w*16 + ln
  int ng = nb + w * 16 + ln;
  float s = 0.f, ss = 0.f;
#pragma unroll
  for (int a = 0; a < 7; ++a) {
#pragma unroll
    for (int rr = 0; rr < 4; ++rr) {
      int t = a * 16 + q * 4 + rr;
      float v = acc[a][rr];
      if (t < 100) {
        if (BF16OUT) ((__bf16*)Yout)[(size_t)t * N + ng] = (__bf16)v;
        else         ((float*)Yout)[(size_t)t * N + ng] = v;
        s += v; ss += v * v;
      }
    }
  }
  if (STATS) {
    s += __shfl_xor(s, 16); ss += __shfl_xor(ss, 16);
    s += __shfl_xor(s, 32); ss += __shfl_xor(ss, 32);
    if (q == 0) {
      int o = ng & (COUTP - 1);
      atomicAdd(&stats[o], s);
      atomicAdd(&stats[COUTP + o], ss);
    }
  }
}

// normalize + relu, bf16x8 vectorized: 409600 threads, 8 channels each
__global__ __launch_bounds__(256)
void bn_apply_relu8(const __bf16* __restrict__ h, const float* __restrict__ stats,
                    const float* __restrict__ gamma, const float* __restrict__ beta,
                    __bf16* __restrict__ hb) {
  int idx = blockIdx.x * 256 + threadIdx.x;
  int co = (idx & 31) * 8;
  size_t row = (size_t)(idx >> 5);
  const __bf16* src = h + row * 256 + co;
  __bf16* dst = hb + row * 256 + co;
  uint4 raw = *(const uint4*)src;
  const ushort_t* pr = (const ushort_t*)&raw;
  uint4 outv;
  ushort_t* po = (ushort_t*)&outv;
#pragma unroll
  for (int j = 0; j < 8; ++j) {
    int c = co + j;
    float mean = stats[c] * (1.f / 12800.f);
    float var = stats[256 + c] * (1.f / 12800.f) - mean * mean;
    float inv = rsqrtf(var + 1e-5f) * gamma[c];
    uint32 u = (uint32)pr[j] << 16;
    float xv; __builtin_memcpy(&xv, &u, 4);
    float v = (xv - mean) * inv + beta[c];
    v = fmaxf(v, 0.f);
    __bf16 bv = (__bf16)v;
    po[j] = *(const ushort_t*)&bv;
  }
  *(uint4*)dst = outv;
}

// softmax over 20 logits, sum over T — one block per b, LDS reduce, no atomics
__global__ __launch_bounds__(128)
void softmax_sum2(const float* __restrict__ y3, float* __restrict__ out) {
  __shared__ float sm[100][21];
  int b = blockIdx.x;   // 128
  int t = threadIdx.x;  // 128 (100 active phase 1)
  if (t < 100) {
    const float* r = y3 + ((size_t)t * B_SZ + b) * 32;
    float v[20], m = -1e30f;
#pragma unroll
    for (int o = 0; o < 20; ++o) { v[o] = r[o]; m = fmaxf(m, v[o]); }
    float s = 0.f;
#pragma unroll
    for (int o = 0; o < 20; ++o) { v[o] = expf(v[o] - m); s += v[o]; }
    float inv = 1.f / s;
#pragma unroll
    for (int o = 0; o < 20; ++o) sm[t][o] = v[o] * inv;
  }
  __syncthreads();
  if (t < 20) {
    float acc = 0.f;
    for (int tt = 0; tt < 100; ++tt) acc += sm[tt][t];
    out[b * 20 + t] = acc;
  }
}

// ---------------------------------------------------------------------------

extern "C" void kernel_launch(void* const* d_in, const int* in_sizes, int n_in,
                              void* d_out, int out_size, void* d_ws, size_t ws_size,
                              hipStream_t stream) {
  const float* x  = (const float*)d_in[0];
  const float* W1 = (const float*)d_in[1];
  const float* P1 = (const float*)d_in[2];
  const float* W2 = (const float*)d_in[3];
  const float* P2 = (const float*)d_in[4];
  const float* W3 = (const float*)d_in[5];
  const float* P3 = (const float*)d_in[6];
  const float* g1 = (const float*)d_in[7];
  const float* b1 = (const float*)d_in[8];
  const float* g2 = (const float*)d_in[9];
  const float* b2 = (const float*)d_in[10];
  float* out = (float*)d_out;

  constexpr size_t XB_B  = (size_t)M_ROWS * 704 * 2;
  constexpr size_t Z_B   = (size_t)608 * 32768 * 2;
  constexpr size_t Y12_B = (size_t)M_ROWS * 256 * 2;
  constexpr size_t Y3_B  = (size_t)M_ROWS * 32 * 4;
  constexpr size_t H_B   = (size_t)M_ROWS * 256 * 2;
  constexpr size_t W1_B  = (size_t)R_RANK * 256 * 704 * 2;
  constexpr size_t W2_B  = (size_t)R_RANK * 256 * 256 * 2;
  constexpr size_t W3_B  = (size_t)R_RANK * 32 * 256 * 2;
  constexpr size_t AF_B  = (size_t)112 * 608 * 2;
  constexpr size_t ST_B  = 4096;
  constexpr size_t TOTAL = XB_B + Z_B + Y12_B + Y3_B + H_B + W1_B + W2_B + W3_B + AF_B + ST_B;
  if (ws_size < TOTAL) return;

  char* ws = (char*)d_ws;
  size_t off = 0;
  __bf16* Xb   = (__bf16*)(ws + off); off += XB_B;
  __bf16* Zb   = (__bf16*)(ws + off); off += Z_B;
  __bf16* Yb   = (__bf16*)(ws + off); off += Y12_B;
  float*  Y3f  = (float*)(ws + off);  off += Y3_B;
  __bf16* Hb   = (__bf16*)(ws + off); off += H_B;
  __bf16* Wr1  = (__bf16*)(ws + off); off += W1_B;
  __bf16* Wr2  = (__bf16*)(ws + off); off += W2_B;
  __bf16* Wr3  = (__bf16*)(ws + off); off += W3_B;
  __bf16* Afir = (__bf16*)(ws + off); off += AF_B;
  float*  stats1 = (float*)(ws + off);
  float*  stats2 = stats1 + 512;

  // one fused setup dispatch: 256+256+32+267+12800+1 blocks
  setup_all<<<dim3(13612), 256, 0, stream>>>(x, W1, P1, W2, P2, W3, P3,
                                             Xb, Wr1, Wr2, Wr3, Afir, stats1);

  // layer 1
  gemm_rk<704, 128, 2, 2, 8><<<dim3(100, 12), 256, 0, stream>>>(Xb, Wr1, Zb);
  fir_gemm<256, true, true><<<dim3(512), 256, 0, stream>>>(Afir, Zb, Yb, stats1, 32768);
  bn_apply_relu8<<<dim3(1600), 256, 0, stream>>>(Yb, stats1, g1, b1, Hb);

  // layer 2
  gemm_rk<256, 128, 2, 2, 8><<<dim3(100, 12), 256, 0, stream>>>(Hb, Wr2, Zb);
  fir_gemm<256, true, true><<<dim3(512), 256, 0, stream>>>(Afir, Zb, Yb, stats2, 32768);
  bn_apply_relu8<<<dim3(1600), 256, 0, stream>>>(Yb, stats2, g2, b2, Hb);

  // layer 3 (COUTP=32, N=4096)
  gemm_rk<256, 64, 2, 2, 5><<<dim3(100, 3), 256, 0, stream>>>(Hb, Wr3, Zb);
  fir_gemm<32, false, false><<<dim3(64), 256, 0, stream>>>(Afir, Zb, Y3f, nullptr, 4096);

  // softmax over channels, sum over time (atomic-free)
  softmax_sum2<<<dim3(128), 128, 0, stream>>>(Y3f, out);
}

// Round 5
// 211.966 us; speedup vs baseline: 2.8554x; 1.1991x over previous
//
#include <hip/hip_runtime.h>
#include <stdint.h>

// ---------------------------------------------------------------------------
// d128snn_delays, round 5: rank-5 CHEBYSHEV DCLS + FIR-as-GEMM, BK=64.
//   K_norm(p,l): exp(-(u-v)^2/2) with u=l'/12, v=p/12 equals
//   exp(-u^2/2)exp(-v^2/2)exp(uv); exp(uv) = I0(v) + 2*sum_{r>=1} I_r(v)T_r(u)
//   truncated at r<=4 (abs err <= 6e-4, better than rank-6 Taylor).
//   Layer: Z_r = X @ W_r^T (gemm_rk64), Y = Afir @ Z (fir_gemm64, fused BN
//   stats; L3 variant fuses softmax+time-sum and writes out directly).
// ---------------------------------------------------------------------------

#define T_LEN 100
#define B_SZ  128
#define M_ROWS 12800
#define R_RANK 5
#define K_FIR 512

typedef __bf16 v8bf __attribute__((ext_vector_type(8)));
typedef float  v4f  __attribute__((ext_vector_type(4)));
typedef unsigned int uint32;
typedef unsigned short ushort_t;

// PHI[tau][r] = exp(-u^2/2) * T_r(u), u = (tau-12)/12  (Chebyshev basis)
struct PhiT { float v[25][R_RANK]; };
constexpr double cexp_(double x) {
  double s = 1.0, t = 1.0;
  for (int n = 1; n < 30; ++n) { t = t * x / n; s += t; }
  return s;
}
constexpr PhiT make_phi() {
  PhiT P{};
  for (int tau = 0; tau < 25; ++tau) {
    double u = (tau - 12) / 12.0;
    double g = cexp_(-0.5 * u * u);
    double T0 = 1.0, T1 = u;
    P.v[tau][0] = (float)(g * T0);
    P.v[tau][1] = (float)(g * T1);
    for (int r = 2; r < R_RANK; ++r) {
      double T2 = 2.0 * u * T1 - T0;
      P.v[tau][r] = (float)(g * T2);
      T0 = T1; T1 = T2;
    }
  }
  return P;
}
constexpr PhiT PHI = make_phi();

__device__ __forceinline__ void gl_lds16(const void* g, void* l) {
  __builtin_amdgcn_global_load_lds(
      (const __attribute__((address_space(1))) char*)g,
      (__attribute__((address_space(3))) char*)l, 16, 0, 0);
}

// ---------------------------------------------------------------------------
// Fused setup: 3x build_wr (Chebyshev coeffs) + build_afir + fill_xb + stats0.
// ---------------------------------------------------------------------------
__device__ __forceinline__ void build_wr_body(
    const float* __restrict__ W, const float* __restrict__ P,
    __bf16* __restrict__ Wr, int CIN, int CINP, int COUT, int COUTP,
    int NRANK_OUT, int o) {
  for (int i = threadIdx.x; i < CINP; i += blockDim.x) {
    bool valid = (o < COUT) && (i < CIN);
    float w = valid ? W[(size_t)o * CIN + i] : 0.f;
    float p = valid ? P[(size_t)o * CIN + i] : 0.f;
    float S = 0.f;
#pragma unroll
    for (int l = 0; l < 25; ++l) {
      float d = ((float)(l - 12) - p) * (1.f / 12.f);
      S += expf(-0.5f * d * d);
    }
    float v = p * (1.f / 12.f);
    float g = w * expf(-0.5f * v * v) / (S + 1e-7f);
    // modified Bessel I_r(v), r = 0..4, 7-term series (|v|<=1)
    float h = 0.5f * v, hh = h * h;
    float Ir[R_RANK];
    float pw = 1.f;  // h^r / r!
#pragma unroll
    for (int r = 0; r < R_RANK; ++r) {
      float term = pw, sum = pw;
#pragma unroll
      for (int m = 1; m <= 6; ++m) {
        term *= hh / (float)(m * (m + r));
        sum += term;
      }
      Ir[r] = sum;
      pw *= h / (float)(r + 1);
    }
    for (int r = 0; r < NRANK_OUT; ++r) {
      float c = (r < R_RANK) ? g * ((r == 0) ? 1.f : 2.f) * Ir[r] : 0.f;
      Wr[((size_t)r * COUTP + o) * CINP + i] = (__bf16)c;
    }
  }
}

__global__ void setup_all(const float* __restrict__ x,
                          const float* __restrict__ W1, const float* __restrict__ P1,
                          const float* __restrict__ W2, const float* __restrict__ P2,
                          const float* __restrict__ W3, const float* __restrict__ P3,
                          __bf16* __restrict__ Xb, __bf16* __restrict__ Wr1,
                          __bf16* __restrict__ Wr2, __bf16* __restrict__ Wr3,
                          __bf16* __restrict__ Af, float* __restrict__ stats) {
  int blk = blockIdx.x;
  if (blk < 256) { build_wr_body(W1, P1, Wr1, 700, 704, 256, 256, 5, blk); return; }
  blk -= 256;
  if (blk < 256) { build_wr_body(W2, P2, Wr2, 256, 256, 256, 256, 5, blk); return; }
  blk -= 256;
  if (blk < 32) { build_wr_body(W3, P3, Wr3, 256, 256, 20, 32, 6, blk); return; }
  blk -= 32;
  if (blk < 224) {  // Afir (112 x 512): [t][r*100+s] = PHI[s-t+24][r], else 0
    int idx = blk * 256 + threadIdx.x;
    int t = idx >> 9, k = idx & 511;
    float v = 0.f;
    if (t < 100 && k < 500) {
      int r = k / 100, s = k - r * 100;
      int tau = s - t + 24;
      if (tau >= 0 && tau < 25) v = PHI.v[tau][r];
    }
    Af[idx] = (__bf16)v;
    return;
  }
  blk -= 224;
  if (blk < 12800) {  // x (B,T,700) f32 -> Xb (T,B,704) bf16
    int t = blk >> 7, b = blk & 127;
    const float* src = x + ((size_t)b * T_LEN + t) * 700;
    __bf16* dst = Xb + (size_t)blk * 704;
    for (int c = threadIdx.x; c < 704; c += 256) dst[c] = (c < 700) ? (__bf16)src[c] : (__bf16)0.f;
    return;
  }
  blk -= 12800;
  if (blk == 0) {
    for (int i = threadIdx.x; i < 1024; i += 256) stats[i] = 0.f;
  }
}

// ---------------------------------------------------------------------------
// Main GEMM, BK=64: Z[k=(r,t)][n=(b,o)] = X @ Wr^T.
// LDS: [row][64] with 8-elem kgroup slot s holding logical group s^(row&7);
// frag read for k-step s,quad q: logical (s*4+q) -> phys ((s*4+q)^(row&7)).
// ---------------------------------------------------------------------------
template <int CINP, int BLK_N, int WROWS, int WCOLS, int CO_SH>
__global__ __launch_bounds__(256, 2)
void gemm_rk64(const __bf16* __restrict__ A, const __bf16* __restrict__ Bm,
               __bf16* __restrict__ Z) {
  constexpr int COUTP = 1 << CO_SH;
  constexpr int WM = 128 / WROWS;
  constexpr int WN = BLK_N / WCOLS;
  constexpr int RM = WM / 16;
  constexpr int RN = WN / 16;
  __shared__ __align__(16) __bf16 sA[128 * 64];
  __shared__ __align__(16) __bf16 sB[BLK_N * 64];

  const int tid = threadIdx.x;
  const int w = tid >> 6, lane = tid & 63;
  const int q = lane >> 4, ln = lane & 15;
  const int wrow = w / WCOLS, wcol = w % WCOLS;
  const int srow8 = lane >> 3;
  const int s8 = lane & 7;

  const int t0 = blockIdx.x;
  const int oc = blockIdx.y * BLK_N;
  const __bf16* Abase = A + (size_t)t0 * 128 * CINP;
  const __bf16* Bbase = Bm + (size_t)oc * CINP;

  v4f acc[RM][RN];
#pragma unroll
  for (int a = 0; a < RM; ++a)
#pragma unroll
    for (int b = 0; b < RN; ++b) acc[a][b] = v4f{0.f, 0.f, 0.f, 0.f};

  for (int ic = 0; ic < CINP; ic += 64) {
    for (int j = w; j < 16; j += 4) {  // A: 128 rows, 8 rows/issue
      int m = j * 8 + srow8;
      int g = s8 ^ (m & 7);
      gl_lds16(Abase + (size_t)m * CINP + ic + g * 8, &sA[j * 512]);
    }
    for (int j = w; j < BLK_N / 8; j += 4) {  // B
      int n = j * 8 + srow8;
      int g = s8 ^ (n & 7);
      gl_lds16(Bbase + (size_t)n * CINP + ic + g * 8, &sB[j * 512]);
    }
    __syncthreads();

#pragma unroll
    for (int s = 0; s < 2; ++s) {
      v8bf af[RM], bfr[RN];
#pragma unroll
      for (int a = 0; a < RM; ++a) {
        int m = wrow * WM + a * 16 + ln;
        af[a] = *(const v8bf*)&sA[m * 64 + ((((s << 2) | q) ^ (m & 7)) * 8)];
      }
#pragma unroll
      for (int b = 0; b < RN; ++b) {
        int n = wcol * WN + b * 16 + ln;
        bfr[b] = *(const v8bf*)&sB[n * 64 + ((((s << 2) | q) ^ (n & 7)) * 8)];
      }
#pragma unroll
      for (int a = 0; a < RM; ++a)
#pragma unroll
        for (int b = 0; b < RN; ++b)
          acc[a][b] = __builtin_amdgcn_mfma_f32_16x16x32_bf16(af[a], bfr[b], acc[a][b], 0, 0, 0);
    }
    __syncthreads();
  }

  // C/D: col=lane&15, row=quad*4+reg (m89-verified)
#pragma unroll
  for (int a = 0; a < RM; ++a) {
#pragma unroll
    for (int b = 0; b < RN; ++b) {
      int n = oc + wcol * WN + b * 16 + ln;
      int r = n >> CO_SH, o = n & (COUTP - 1);
#pragma unroll
      for (int rr = 0; rr < 4; ++rr) {
        int m = t0 * 128 + wrow * WM + a * 16 + q * 4 + rr;
        Z[((size_t)r * M_ROWS + m) * COUTP + o] = (__bf16)acc[a][b][rr];
      }
    }
  }
}

// ---------------------------------------------------------------------------
// FIR GEMM, BK=64, K=512: Y(112 x 64-slice) = Afir(112x512) @ Z(512xN).
// B transposed in LDS: 256 threads = 32 k-pairs x 8 n-octets, exactly one
// dwordx4 pair per thread per iter; [n][35-dword stride] => 2 lanes/bank.
// STATS: fused BN sum/sumsq.  SOFTMAX (L3): in-LDS softmax over o + time-sum,
// writes out[b][o] directly.
// ---------------------------------------------------------------------------
template <int COUTP, bool STATS, bool SOFTMAX>
__global__ __launch_bounds__(256, 2)
void fir_gemm64(const __bf16* __restrict__ Af, const __bf16* __restrict__ Z,
                __bf16* __restrict__ Yout, float* __restrict__ stats,
                float* __restrict__ outp, int N) {
  __shared__ __align__(16) unsigned char smem[26624];
  __bf16* sA = (__bf16*)smem;               // 112*64*2 = 14336 B
  uint32* sBu = (uint32*)(smem + 14336);    // 64*35*4  =  8960 B

  const int tid = threadIdx.x;
  const int w = tid >> 6, lane = tid & 63;
  const int q = lane >> 4, ln = lane & 15;
  const int srow8 = lane >> 3, s8 = lane & 7;
  const int kp = tid >> 3;    // 0..31
  const int noct = tid & 7;   // 0..7
  const int nb = blockIdx.x * 64;

  v4f acc[7];
#pragma unroll
  for (int a = 0; a < 7; ++a) acc[a] = v4f{0.f, 0.f, 0.f, 0.f};

  for (int kc = 0; kc < K_FIR; kc += 64) {
    // stage A (112 x 64)
    for (int j = w; j < 14; j += 4) {
      int m = j * 8 + srow8;
      int g = s8 ^ (m & 7);
      gl_lds16(Af + (size_t)m * K_FIR + kc + g * 8, &sA[j * 512]);
    }
    // stage B transposed
    const __bf16* zp = Z + (size_t)(kc + kp * 2) * N + nb + noct * 8;
    uint4 r0 = *(const uint4*)zp;
    uint4 r1 = *(const uint4*)(zp + N);
    const ushort_t* p0 = (const ushort_t*)&r0;
    const ushort_t* p1 = (const ushort_t*)&r1;
#pragma unroll
    for (int j = 0; j < 8; ++j) {
      uint32 val = (uint32)p0[j] | ((uint32)p1[j] << 16);
      sBu[(noct * 8 + j) * 35 + kp] = val;
    }
    __syncthreads();

#pragma unroll
    for (int s = 0; s < 2; ++s) {
      v8bf af[7];
#pragma unroll
      for (int a = 0; a < 7; ++a) {
        int m = a * 16 + ln;
        af[a] = *(const v8bf*)&sA[m * 64 + ((((s << 2) | q) ^ (m & 7)) * 8)];
      }
      int base = (w * 16 + ln) * 35 + s * 16 + q * 4;
      uint32 tmp[4] = {sBu[base], sBu[base + 1], sBu[base + 2], sBu[base + 3]};
      v8bf bfr = *(const v8bf*)tmp;
#pragma unroll
      for (int a = 0; a < 7; ++a)
        acc[a] = __builtin_amdgcn_mfma_f32_16x16x32_bf16(af[a], bfr, acc[a], 0, 0, 0);
    }
    __syncthreads();
  }

  int ng = nb + w * 16 + ln;
  if (!SOFTMAX) {
    float s = 0.f, ss = 0.f;
#pragma unroll
    for (int a = 0; a < 7; ++a) {
#pragma unroll
      for (int rr = 0; rr < 4; ++rr) {
        int t = a * 16 + q * 4 + rr;
        float v = acc[a][rr];
        if (t < 100) {
          Yout[(size_t)t * N + ng] = (__bf16)v;
          s += v; ss += v * v;
        }
      }
    }
    if (STATS) {
      s += __shfl_xor(s, 16); ss += __shfl_xor(ss, 16);
      s += __shfl_xor(s, 32); ss += __shfl_xor(ss, 32);
      if (q == 0) {
        int o = ng & (COUTP - 1);
        atomicAdd(&stats[o], s);
        atomicAdd(&stats[COUTP + o], ss);
      }
    }
  } else {
    // L3: this block holds all t (rows) and all o for 2 batch entries.
    float* smx = (float*)smem;               // [100][65] = 26000 B (reuses sA/sB)
    float* lacc = (float*)(smem + 26000);    // 40 floats
    int col = w * 16 + ln;
#pragma unroll
    for (int a = 0; a < 7; ++a) {
#pragma unroll
      for (int rr = 0; rr < 4; ++rr) {
        int t = a * 16 + q * 4 + rr;
        if (t < 100) smx[t * 65 + col] = acc[a][rr];
      }
    }
    if (tid < 64) lacc[tid & 63] = 0.f;
    __syncthreads();
    if (tid < 200) {
      int bl = tid / 100, t = tid - bl * 100;
      const float* rr = &smx[t * 65 + bl * 32];
      float v[20], m = -1e30f;
#pragma unroll
      for (int o = 0; o < 20; ++o) { v[o] = rr[o]; m = fmaxf(m, v[o]); }
      float sum = 0.f;
#pragma unroll
      for (int o = 0; o < 20; ++o) { v[o] = expf(v[o] - m); sum += v[o]; }
      float inv = 1.f / sum;
#pragma unroll
      for (int o = 0; o < 20; ++o) atomicAdd(&lacc[bl * 20 + o], v[o] * inv);
    }
    __syncthreads();
    if (tid < 40) {
      int bl = tid / 20, o = tid - bl * 20;
      int b = (nb >> 5) + bl;
      outp[b * 20 + o] = lacc[bl * 20 + o];
    }
  }
}

// normalize + relu, bf16x8 vectorized
__global__ __launch_bounds__(256)
void bn_apply_relu8(const __bf16* __restrict__ h, const float* __restrict__ stats,
                    const float* __restrict__ gamma, const float* __restrict__ beta,
                    __bf16* __restrict__ hb) {
  int idx = blockIdx.x * 256 + threadIdx.x;
  int co = (idx & 31) * 8;
  size_t row = (size_t)(idx >> 5);
  const __bf16* src = h + row * 256 + co;
  __bf16* dst = hb + row * 256 + co;
  uint4 raw = *(const uint4*)src;
  const ushort_t* pr = (const ushort_t*)&raw;
  uint4 outv;
  ushort_t* po = (ushort_t*)&outv;
#pragma unroll
  for (int j = 0; j < 8; ++j) {
    int c = co + j;
    float mean = stats[c] * (1.f / 12800.f);
    float var = stats[256 + c] * (1.f / 12800.f) - mean * mean;
    float inv = rsqrtf(var + 1e-5f) * gamma[c];
    uint32 u = (uint32)pr[j] << 16;
    float xv; __builtin_memcpy(&xv, &u, 4);
    float v = (xv - mean) * inv + beta[c];
    v = fmaxf(v, 0.f);
    __bf16 bv = (__bf16)v;
    po[j] = *(const ushort_t*)&bv;
  }
  *(uint4*)dst = outv;
}

// ---------------------------------------------------------------------------

extern "C" void kernel_launch(void* const* d_in, const int* in_sizes, int n_in,
                              void* d_out, int out_size, void* d_ws, size_t ws_size,
                              hipStream_t stream) {
  const float* x  = (const float*)d_in[0];
  const float* W1 = (const float*)d_in[1];
  const float* P1 = (const float*)d_in[2];
  const float* W2 = (const float*)d_in[3];
  const float* P2 = (const float*)d_in[4];
  const float* W3 = (const float*)d_in[5];
  const float* P3 = (const float*)d_in[6];
  const float* g1 = (const float*)d_in[7];
  const float* b1 = (const float*)d_in[8];
  const float* g2 = (const float*)d_in[9];
  const float* b2 = (const float*)d_in[10];
  float* out = (float*)d_out;

  constexpr size_t XB_B  = (size_t)M_ROWS * 704 * 2;        // 18,022,400
  constexpr size_t Z_B   = (size_t)K_FIR * 32768 * 2;       // 33,554,432
  constexpr size_t Y12_B = (size_t)M_ROWS * 256 * 2;        //  6,553,600
  constexpr size_t H_B   = (size_t)M_ROWS * 256 * 2;        //  6,553,600
  constexpr size_t W1_B  = (size_t)5 * 256 * 704 * 2;       //  1,802,240
  constexpr size_t W2_B  = (size_t)5 * 256 * 256 * 2;       //    655,360
  constexpr size_t W3_B  = (size_t)6 * 32 * 256 * 2;        //     98,304
  constexpr size_t AF_B  = (size_t)112 * K_FIR * 2;         //    114,688
  constexpr size_t ST_B  = 4096;
  constexpr size_t TOTAL = XB_B + Z_B + Y12_B + H_B + W1_B + W2_B + W3_B + AF_B + ST_B;
  if (ws_size < TOTAL) return;

  char* ws = (char*)d_ws;
  size_t off = 0;
  __bf16* Xb   = (__bf16*)(ws + off); off += XB_B;
  __bf16* Zb   = (__bf16*)(ws + off); off += Z_B;
  __bf16* Yb   = (__bf16*)(ws + off); off += Y12_B;
  __bf16* Hb   = (__bf16*)(ws + off); off += H_B;
  __bf16* Wr1  = (__bf16*)(ws + off); off += W1_B;
  __bf16* Wr2  = (__bf16*)(ws + off); off += W2_B;
  __bf16* Wr3  = (__bf16*)(ws + off); off += W3_B;
  __bf16* Afir = (__bf16*)(ws + off); off += AF_B;
  float*  stats1 = (float*)(ws + off);
  float*  stats2 = stats1 + 512;

  // fused setup: 256+256+32+224+12800+1 blocks
  setup_all<<<dim3(13569), 256, 0, stream>>>(x, W1, P1, W2, P2, W3, P3,
                                             Xb, Wr1, Wr2, Wr3, Afir, stats1);

  // layer 1: GEMM (12800 x 1280 x 704)
  gemm_rk64<704, 128, 2, 2, 8><<<dim3(100, 10), 256, 0, stream>>>(Xb, Wr1, Zb);
  fir_gemm64<256, true, false><<<dim3(512), 256, 0, stream>>>(Afir, Zb, Yb, stats1, nullptr, 32768);
  bn_apply_relu8<<<dim3(1600), 256, 0, stream>>>(Yb, stats1, g1, b1, Hb);

  // layer 2: GEMM (12800 x 1280 x 256)
  gemm_rk64<256, 128, 2, 2, 8><<<dim3(100, 10), 256, 0, stream>>>(Hb, Wr2, Zb);
  fir_gemm64<256, true, false><<<dim3(512), 256, 0, stream>>>(Afir, Zb, Yb, stats2, nullptr, 32768);
  bn_apply_relu8<<<dim3(1600), 256, 0, stream>>>(Yb, stats2, g2, b2, Hb);

  // layer 3: GEMM (12800 x 192 x 256), then FIR + fused softmax/time-sum
  gemm_rk64<256, 64, 2, 2, 5><<<dim3(100, 3), 256, 0, stream>>>(Hb, Wr3, Zb);
  fir_gemm64<32, false, true><<<dim3(64), 256, 0, stream>>>(Afir, Zb, nullptr, nullptr, out, 4096);
}

// Round 6
// 209.813 us; speedup vs baseline: 2.8847x; 1.0103x over previous
//
#include <hip/hip_runtime.h>
#include <stdint.h>

// ---------------------------------------------------------------------------
// d128snn_delays, round 6: rank-4 CHEBYSHEV DCLS + FIR-as-GEMM (BK=64) with
// BN+ReLU inlined into the A-staging of the next layer's GEMM.
//   exp(uv) = I0(v) + 2 sum_{r>=1} I_r(v) T_r(u), truncated r<=3
//   (abs err <= 0.006 on exp(uv), ~1.5% on far taps — below bf16 margin).
//   Layer: Z_r = X @ W_r^T (gemm_rk64), Y = Afir @ Z (fir_gemm64, fused BN
//   stats; L3 variant fuses softmax+time-sum). gemm2/gemm3 apply BN+ReLU
//   in-staging from (Y, stats) — no bn_apply kernel, no H buffer.
// ---------------------------------------------------------------------------

#define T_LEN 100
#define B_SZ  128
#define M_ROWS 12800
#define R_RANK 4
#define K_FIR 448

typedef __bf16 v8bf __attribute__((ext_vector_type(8)));
typedef float  v4f  __attribute__((ext_vector_type(4)));
typedef unsigned int uint32;
typedef unsigned short ushort_t;

// PHI[tau][r] = exp(-u^2/2) * T_r(u), u = (tau-12)/12  (Chebyshev basis)
struct PhiT { float v[25][R_RANK]; };
constexpr double cexp_(double x) {
  double s = 1.0, t = 1.0;
  for (int n = 1; n < 30; ++n) { t = t * x / n; s += t; }
  return s;
}
constexpr PhiT make_phi() {
  PhiT P{};
  for (int tau = 0; tau < 25; ++tau) {
    double u = (tau - 12) / 12.0;
    double g = cexp_(-0.5 * u * u);
    double T0 = 1.0, T1 = u;
    P.v[tau][0] = (float)(g * T0);
    P.v[tau][1] = (float)(g * T1);
    for (int r = 2; r < R_RANK; ++r) {
      double T2 = 2.0 * u * T1 - T0;
      P.v[tau][r] = (float)(g * T2);
      T0 = T1; T1 = T2;
    }
  }
  return P;
}
constexpr PhiT PHI = make_phi();

__device__ __forceinline__ void gl_lds16(const void* g, void* l) {
  __builtin_amdgcn_global_load_lds(
      (const __attribute__((address_space(1))) char*)g,
      (__attribute__((address_space(3))) char*)l, 16, 0, 0);
}

// ---------------------------------------------------------------------------
// Fused setup: 3x build_wr (Chebyshev/Bessel coeffs) + build_afir + fill_xb
// + stats zero.
// ---------------------------------------------------------------------------
__device__ __forceinline__ void build_wr_body(
    const float* __restrict__ W, const float* __restrict__ P,
    __bf16* __restrict__ Wr, int CIN, int CINP, int COUT, int COUTP, int o) {
  for (int i = threadIdx.x; i < CINP; i += blockDim.x) {
    bool valid = (o < COUT) && (i < CIN);
    float w = valid ? W[(size_t)o * CIN + i] : 0.f;
    float p = valid ? P[(size_t)o * CIN + i] : 0.f;
    float S = 0.f;
#pragma unroll
    for (int l = 0; l < 25; ++l) {
      float d = ((float)(l - 12) - p) * (1.f / 12.f);
      S += expf(-0.5f * d * d);
    }
    float v = p * (1.f / 12.f);
    float g = w * expf(-0.5f * v * v) / (S + 1e-7f);
    // modified Bessel I_r(v), r = 0..3, 7-term series (|v|<=1)
    float h = 0.5f * v, hh = h * h;
    float pw = 1.f;  // h^r / r!
#pragma unroll
    for (int r = 0; r < R_RANK; ++r) {
      float term = pw, sum = pw;
#pragma unroll
      for (int m = 1; m <= 6; ++m) {
        term *= hh / (float)(m * (m + r));
        sum += term;
      }
      float c = g * ((r == 0) ? 1.f : 2.f) * sum;
      Wr[((size_t)r * COUTP + o) * CINP + i] = (__bf16)c;
      pw *= h / (float)(r + 1);
    }
  }
}

__global__ void setup_all(const float* __restrict__ x,
                          const float* __restrict__ W1, const float* __restrict__ P1,
                          const float* __restrict__ W2, const float* __restrict__ P2,
                          const float* __restrict__ W3, const float* __restrict__ P3,
                          __bf16* __restrict__ Xb, __bf16* __restrict__ Wr1,
                          __bf16* __restrict__ Wr2, __bf16* __restrict__ Wr3,
                          __bf16* __restrict__ Af, float* __restrict__ stats) {
  int blk = blockIdx.x;
  if (blk < 256) { build_wr_body(W1, P1, Wr1, 700, 704, 256, 256, blk); return; }
  blk -= 256;
  if (blk < 256) { build_wr_body(W2, P2, Wr2, 256, 256, 256, 256, blk); return; }
  blk -= 256;
  if (blk < 32) { build_wr_body(W3, P3, Wr3, 256, 256, 20, 32, blk); return; }
  blk -= 32;
  if (blk < 196) {  // Afir (112 x 448): [t][r*100+s] = PHI[s-t+24][r], else 0
    int idx = blk * 256 + threadIdx.x;
    if (idx < 112 * 448) {
      int t = idx / 448, k = idx - t * 448;
      float v = 0.f;
      if (t < 100 && k < 400) {
        int r = k / 100, s = k - r * 100;
        int tau = s - t + 24;
        if (tau >= 0 && tau < 25) v = PHI.v[tau][r];
      }
      Af[idx] = (__bf16)v;
    }
    return;
  }
  blk -= 196;
  if (blk < 12800) {  // x (B,T,700) f32 -> Xb (T,B,704) bf16
    int t = blk >> 7, b = blk & 127;
    const float* src = x + ((size_t)b * T_LEN + t) * 700;
    __bf16* dst = Xb + (size_t)blk * 704;
    for (int c = threadIdx.x; c < 704; c += 256) dst[c] = (c < 700) ? (__bf16)src[c] : (__bf16)0.f;
    return;
  }
  blk -= 12800;
  if (blk == 0) {
    for (int i = threadIdx.x; i < 1024; i += 256) stats[i] = 0.f;
  }
}

// ---------------------------------------------------------------------------
// Main GEMM, BK=64: Z[k=(r,t)][n=(b,o)] = A' @ Wr^T, where A' = A (BN=false)
// or relu(A*scale+shift) per K-channel (BN=true; scale/shift from stats).
// LDS: [row][64], 8-elem kgroup slot s holds logical group s^(row&7).
// BN staging writes the IDENTICAL LDS bytes gl_lds would (lane slot =
// lane&7, logical group g = (lane&7)^(lane>>3), lane-constant).
// ---------------------------------------------------------------------------
template <int CINP, int BLK_N, int WROWS, int WCOLS, int CO_SH, bool BN>
__global__ __launch_bounds__(256, 2)
void gemm_rk64(const __bf16* __restrict__ A, const __bf16* __restrict__ Bm,
               __bf16* __restrict__ Z,
               const float* __restrict__ stats, const float* __restrict__ gamma,
               const float* __restrict__ beta) {
  constexpr int COUTP = 1 << CO_SH;
  constexpr int WM = 128 / WROWS;
  constexpr int WN = BLK_N / WCOLS;
  constexpr int RM = WM / 16;
  constexpr int RN = WN / 16;
  __shared__ __align__(16) __bf16 sA[128 * 64];
  __shared__ __align__(16) __bf16 sB[BLK_N * 64];
  __shared__ float sScale[BN ? 256 : 1];
  __shared__ float sShift[BN ? 256 : 1];

  const int tid = threadIdx.x;
  const int w = tid >> 6, lane = tid & 63;
  const int q = lane >> 4, ln = lane & 15;
  const int wrow = w / WCOLS, wcol = w % WCOLS;
  const int srow8 = lane >> 3;
  const int s8 = lane & 7;
  const int g_lane = s8 ^ srow8;  // logical kgroup this lane loads (constant)

  const int t0 = blockIdx.x;
  const int oc = blockIdx.y * BLK_N;
  const __bf16* Abase = A + (size_t)t0 * 128 * CINP;
  const __bf16* Bbase = Bm + (size_t)oc * CINP;

  if (BN) {
    int c = tid;  // 256 threads = 256 K-channels
    float mean = stats[c] * (1.f / 12800.f);
    float var = stats[256 + c] * (1.f / 12800.f) - mean * mean;
    float sc = rsqrtf(var + 1e-5f) * gamma[c];
    sScale[c] = sc;
    sShift[c] = beta[c] - mean * sc;
    __syncthreads();
  }

  v4f acc[RM][RN];
#pragma unroll
  for (int a = 0; a < RM; ++a)
#pragma unroll
    for (int b = 0; b < RN; ++b) acc[a][b] = v4f{0.f, 0.f, 0.f, 0.f};

  for (int ic = 0; ic < CINP; ic += 64) {
    if (!BN) {
      for (int j = w; j < 16; j += 4) {  // A: 128 rows, 8 rows/issue
        int m = j * 8 + srow8;
        int g = s8 ^ (m & 7);
        gl_lds16(Abase + (size_t)m * CINP + ic + g * 8, &sA[j * 512]);
      }
    } else {
      // load 8 bf16, apply y*scale+shift, relu, write same LDS slot
      float scl[8], sht[8];
#pragma unroll
      for (int jj = 0; jj < 8; ++jj) {
        scl[jj] = sScale[ic + g_lane * 8 + jj];
        sht[jj] = sShift[ic + g_lane * 8 + jj];
      }
      for (int j = w; j < 16; j += 4) {
        int m = j * 8 + srow8;
        uint4 raw = *(const uint4*)(Abase + (size_t)m * CINP + ic + g_lane * 8);
        const ushort_t* pr = (const ushort_t*)&raw;
        uint4 outv;
        ushort_t* po = (ushort_t*)&outv;
#pragma unroll
        for (int jj = 0; jj < 8; ++jj) {
          uint32 u = (uint32)pr[jj] << 16;
          float yv; __builtin_memcpy(&yv, &u, 4);
          float vv = fmaxf(yv * scl[jj] + sht[jj], 0.f);
          __bf16 bv = (__bf16)vv;
          po[jj] = *(const ushort_t*)&bv;
        }
        *(uint4*)((char*)sA + (size_t)j * 1024 + (size_t)lane * 16) = outv;
      }
    }
    for (int j = w; j < BLK_N / 8; j += 4) {  // B via async DMA
      int n = j * 8 + srow8;
      int g = s8 ^ (n & 7);
      gl_lds16(Bbase + (size_t)n * CINP + ic + g * 8, &sB[j * 512]);
    }
    __syncthreads();

#pragma unroll
    for (int s = 0; s < 2; ++s) {
      v8bf af[RM], bfr[RN];
#pragma unroll
      for (int a = 0; a < RM; ++a) {
        int m = wrow * WM + a * 16 + ln;
        af[a] = *(const v8bf*)&sA[m * 64 + ((((s << 2) | q) ^ (m & 7)) * 8)];
      }
#pragma unroll
      for (int b = 0; b < RN; ++b) {
        int n = wcol * WN + b * 16 + ln;
        bfr[b] = *(const v8bf*)&sB[n * 64 + ((((s << 2) | q) ^ (n & 7)) * 8)];
      }
#pragma unroll
      for (int a = 0; a < RM; ++a)
#pragma unroll
        for (int b = 0; b < RN; ++b)
          acc[a][b] = __builtin_amdgcn_mfma_f32_16x16x32_bf16(af[a], bfr[b], acc[a][b], 0, 0, 0);
    }
    __syncthreads();
  }

  // C/D: col=lane&15, row=quad*4+reg (m89-verified)
#pragma unroll
  for (int a = 0; a < RM; ++a) {
#pragma unroll
    for (int b = 0; b < RN; ++b) {
      int n = oc + wcol * WN + b * 16 + ln;
      int r = n >> CO_SH, o = n & (COUTP - 1);
#pragma unroll
      for (int rr = 0; rr < 4; ++rr) {
        int m = t0 * 128 + wrow * WM + a * 16 + q * 4 + rr;
        Z[((size_t)r * M_ROWS + m) * COUTP + o] = (__bf16)acc[a][b][rr];
      }
    }
  }
}

// ---------------------------------------------------------------------------
// FIR GEMM, BK=64, K=448: Y(112 x 64-slice) = Afir(112x448) @ Z(448xN).
// B transposed in LDS (k-pair packed b32, [n][35-dword stride]).
// STATS: fused BN sum/sumsq.  SOFTMAX (L3): in-LDS softmax over o + time-sum.
// ---------------------------------------------------------------------------
template <int COUTP, bool STATS, bool SOFTMAX>
__global__ __launch_bounds__(256, 2)
void fir_gemm64(const __bf16* __restrict__ Af, const __bf16* __restrict__ Z,
                __bf16* __restrict__ Yout, float* __restrict__ stats,
                float* __restrict__ outp, int N) {
  __shared__ __align__(16) unsigned char smem[26624];
  __bf16* sA = (__bf16*)smem;               // 112*64*2 = 14336 B
  uint32* sBu = (uint32*)(smem + 14336);    // 64*35*4  =  8960 B

  const int tid = threadIdx.x;
  const int w = tid >> 6, lane = tid & 63;
  const int q = lane >> 4, ln = lane & 15;
  const int srow8 = lane >> 3, s8 = lane & 7;
  const int kp = tid >> 3;    // 0..31
  const int noct = tid & 7;   // 0..7
  const int nb = blockIdx.x * 64;

  v4f acc[7];
#pragma unroll
  for (int a = 0; a < 7; ++a) acc[a] = v4f{0.f, 0.f, 0.f, 0.f};

  for (int kc = 0; kc < K_FIR; kc += 64) {
    // stage A (112 x 64)
    for (int j = w; j < 14; j += 4) {
      int m = j * 8 + srow8;
      int g = s8 ^ (m & 7);
      gl_lds16(Af + (size_t)m * K_FIR + kc + g * 8, &sA[j * 512]);
    }
    // stage B transposed
    const __bf16* zp = Z + (size_t)(kc + kp * 2) * N + nb + noct * 8;
    uint4 r0 = *(const uint4*)zp;
    uint4 r1 = *(const uint4*)(zp + N);
    const ushort_t* p0 = (const ushort_t*)&r0;
    const ushort_t* p1 = (const ushort_t*)&r1;
#pragma unroll
    for (int j = 0; j < 8; ++j) {
      uint32 val = (uint32)p0[j] | ((uint32)p1[j] << 16);
      sBu[(noct * 8 + j) * 35 + kp] = val;
    }
    __syncthreads();

#pragma unroll
    for (int s = 0; s < 2; ++s) {
      v8bf af[7];
#pragma unroll
      for (int a = 0; a < 7; ++a) {
        int m = a * 16 + ln;
        af[a] = *(const v8bf*)&sA[m * 64 + ((((s << 2) | q) ^ (m & 7)) * 8)];
      }
      int base = (w * 16 + ln) * 35 + s * 16 + q * 4;
      uint32 tmp[4] = {sBu[base], sBu[base + 1], sBu[base + 2], sBu[base + 3]};
      v8bf bfr = *(const v8bf*)tmp;
#pragma unroll
      for (int a = 0; a < 7; ++a)
        acc[a] = __builtin_amdgcn_mfma_f32_16x16x32_bf16(af[a], bfr, acc[a], 0, 0, 0);
    }
    __syncthreads();
  }

  int ng = nb + w * 16 + ln;
  if (!SOFTMAX) {
    float s = 0.f, ss = 0.f;
#pragma unroll
    for (int a = 0; a < 7; ++a) {
#pragma unroll
      for (int rr = 0; rr < 4; ++rr) {
        int t = a * 16 + q * 4 + rr;
        float v = acc[a][rr];
        if (t < 100) {
          Yout[(size_t)t * N + ng] = (__bf16)v;
          s += v; ss += v * v;
        }
      }
    }
    if (STATS) {
      s += __shfl_xor(s, 16); ss += __shfl_xor(ss, 16);
      s += __shfl_xor(s, 32); ss += __shfl_xor(ss, 32);
      if (q == 0) {
        int o = ng & (COUTP - 1);
        atomicAdd(&stats[o], s);
        atomicAdd(&stats[COUTP + o], ss);
      }
    }
  } else {
    // L3: this block holds all t and all o for 2 batch entries.
    float* smx = (float*)smem;               // [100][65] = 26000 B (reuses sA/sB)
    float* lacc = (float*)(smem + 26000);    // 40 floats
    int col = w * 16 + ln;
#pragma unroll
    for (int a = 0; a < 7; ++a) {
#pragma unroll
      for (int rr = 0; rr < 4; ++rr) {
        int t = a * 16 + q * 4 + rr;
        if (t < 100) smx[t * 65 + col] = acc[a][rr];
      }
    }
    if (tid < 64) lacc[tid & 63] = 0.f;
    __syncthreads();
    if (tid < 200) {
      int bl = tid / 100, t = tid - bl * 100;
      const float* rr = &smx[t * 65 + bl * 32];
      float v[20], m = -1e30f;
#pragma unroll
      for (int o = 0; o < 20; ++o) { v[o] = rr[o]; m = fmaxf(m, v[o]); }
      float sum = 0.f;
#pragma unroll
      for (int o = 0; o < 20; ++o) { v[o] = expf(v[o] - m); sum += v[o]; }
      float inv = 1.f / sum;
#pragma unroll
      for (int o = 0; o < 20; ++o) atomicAdd(&lacc[bl * 20 + o], v[o] * inv);
    }
    __syncthreads();
    if (tid < 40) {
      int bl = tid / 20, o = tid - bl * 20;
      int b = (nb >> 5) + bl;
      outp[b * 20 + o] = lacc[bl * 20 + o];
    }
  }
}

// ---------------------------------------------------------------------------

extern "C" void kernel_launch(void* const* d_in, const int* in_sizes, int n_in,
                              void* d_out, int out_size, void* d_ws, size_t ws_size,
                              hipStream_t stream) {
  const float* x  = (const float*)d_in[0];
  const float* W1 = (const float*)d_in[1];
  const float* P1 = (const float*)d_in[2];
  const float* W2 = (const float*)d_in[3];
  const float* P2 = (const float*)d_in[4];
  const float* W3 = (const float*)d_in[5];
  const float* P3 = (const float*)d_in[6];
  const float* g1 = (const float*)d_in[7];
  const float* b1 = (const float*)d_in[8];
  const float* g2 = (const float*)d_in[9];
  const float* b2 = (const float*)d_in[10];
  float* out = (float*)d_out;

  constexpr size_t XB_B  = (size_t)M_ROWS * 704 * 2;        // 18,022,400
  constexpr size_t Z_B   = (size_t)K_FIR * 32768 * 2;       // 29,360,128
  constexpr size_t Y12_B = (size_t)M_ROWS * 256 * 2;        //  6,553,600
  constexpr size_t W1_B  = (size_t)R_RANK * 256 * 704 * 2;  //  1,441,792
  constexpr size_t W2_B  = (size_t)R_RANK * 256 * 256 * 2;  //    524,288
  constexpr size_t W3_B  = (size_t)R_RANK * 32 * 256 * 2;   //     65,536
  constexpr size_t AF_B  = (size_t)112 * K_FIR * 2;         //    100,352
  constexpr size_t ST_B  = 4096;
  constexpr size_t TOTAL = XB_B + Z_B + Y12_B + W1_B + W2_B + W3_B + AF_B + ST_B;
  if (ws_size < TOTAL) return;

  char* ws = (char*)d_ws;
  size_t off = 0;
  __bf16* Xb   = (__bf16*)(ws + off); off += XB_B;
  __bf16* Zb   = (__bf16*)(ws + off); off += Z_B;
  __bf16* Yb   = (__bf16*)(ws + off); off += Y12_B;   // Y1 then Y2 (reused)
  __bf16* Wr1  = (__bf16*)(ws + off); off += W1_B;
  __bf16* Wr2  = (__bf16*)(ws + off); off += W2_B;
  __bf16* Wr3  = (__bf16*)(ws + off); off += W3_B;
  __bf16* Afir = (__bf16*)(ws + off); off += AF_B;
  float*  stats1 = (float*)(ws + off);
  float*  stats2 = stats1 + 512;

  // fused setup: 256+256+32+196+12800+1 blocks
  setup_all<<<dim3(13541), 256, 0, stream>>>(x, W1, P1, W2, P2, W3, P3,
                                             Xb, Wr1, Wr2, Wr3, Afir, stats1);

  // layer 1: GEMM (12800 x 1024 x 704) -> FIR (+stats)
  gemm_rk64<704, 128, 2, 2, 8, false><<<dim3(100, 8), 256, 0, stream>>>(
      Xb, Wr1, Zb, nullptr, nullptr, nullptr);
  fir_gemm64<256, true, false><<<dim3(512), 256, 0, stream>>>(
      Afir, Zb, Yb, stats1, nullptr, 32768);

  // layer 2: GEMM with inline BN1+ReLU on A (reads Yb+stats1)
  gemm_rk64<256, 128, 2, 2, 8, true><<<dim3(100, 8), 256, 0, stream>>>(
      Yb, Wr2, Zb, stats1, g1, b1);
  fir_gemm64<256, true, false><<<dim3(512), 256, 0, stream>>>(
      Afir, Zb, Yb, stats2, nullptr, 32768);

  // layer 3: GEMM (N=128) with inline BN2+ReLU, then FIR + fused softmax/sum
  gemm_rk64<256, 64, 2, 2, 5, true><<<dim3(100, 2), 256, 0, stream>>>(
      Yb, Wr3, Zb, stats2, g2, b2);
  fir_gemm64<32, false, true><<<dim3(64), 256, 0, stream>>>(
      Afir, Zb, nullptr, nullptr, out, 4096);
}

// Round 7
// 200.852 us; speedup vs baseline: 3.0135x; 1.0446x over previous
//
#include <hip/hip_runtime.h>
#include <stdint.h>

// ---------------------------------------------------------------------------
// d128snn_delays, round 7: rank-4 Chebyshev DCLS + FIR-as-GEMM (BK=64).
// R7: BN+ReLU back to a standalone vectorized kernel (R6's in-staging BN
// added ~280 VALU-cyc/iter to the GEMM critical path — reverted), and
// BLK_N=256 for gemm1/gemm2 to halve A-staging and double MFMA per barrier.
// ---------------------------------------------------------------------------

#define T_LEN 100
#define B_SZ  128
#define M_ROWS 12800
#define R_RANK 4
#define K_FIR 448

typedef __bf16 v8bf __attribute__((ext_vector_type(8)));
typedef float  v4f  __attribute__((ext_vector_type(4)));
typedef unsigned int uint32;
typedef unsigned short ushort_t;

// PHI[tau][r] = exp(-u^2/2) * T_r(u), u = (tau-12)/12  (Chebyshev basis)
struct PhiT { float v[25][R_RANK]; };
constexpr double cexp_(double x) {
  double s = 1.0, t = 1.0;
  for (int n = 1; n < 30; ++n) { t = t * x / n; s += t; }
  return s;
}
constexpr PhiT make_phi() {
  PhiT P{};
  for (int tau = 0; tau < 25; ++tau) {
    double u = (tau - 12) / 12.0;
    double g = cexp_(-0.5 * u * u);
    double T0 = 1.0, T1 = u;
    P.v[tau][0] = (float)(g * T0);
    P.v[tau][1] = (float)(g * T1);
    for (int r = 2; r < R_RANK; ++r) {
      double T2 = 2.0 * u * T1 - T0;
      P.v[tau][r] = (float)(g * T2);
      T0 = T1; T1 = T2;
    }
  }
  return P;
}
constexpr PhiT PHI = make_phi();

__device__ __forceinline__ void gl_lds16(const void* g, void* l) {
  __builtin_amdgcn_global_load_lds(
      (const __attribute__((address_space(1))) char*)g,
      (__attribute__((address_space(3))) char*)l, 16, 0, 0);
}

// ---------------------------------------------------------------------------
// Fused setup: 3x build_wr (Chebyshev/Bessel coeffs) + build_afir + fill_xb
// + stats zero.
// ---------------------------------------------------------------------------
__device__ __forceinline__ void build_wr_body(
    const float* __restrict__ W, const float* __restrict__ P,
    __bf16* __restrict__ Wr, int CIN, int CINP, int COUT, int COUTP, int o) {
  for (int i = threadIdx.x; i < CINP; i += blockDim.x) {
    bool valid = (o < COUT) && (i < CIN);
    float w = valid ? W[(size_t)o * CIN + i] : 0.f;
    float p = valid ? P[(size_t)o * CIN + i] : 0.f;
    float S = 0.f;
#pragma unroll
    for (int l = 0; l < 25; ++l) {
      float d = ((float)(l - 12) - p) * (1.f / 12.f);
      S += expf(-0.5f * d * d);
    }
    float v = p * (1.f / 12.f);
    float g = w * expf(-0.5f * v * v) / (S + 1e-7f);
    // modified Bessel I_r(v), r = 0..3, 7-term series (|v|<=1)
    float h = 0.5f * v, hh = h * h;
    float pw = 1.f;  // h^r / r!
#pragma unroll
    for (int r = 0; r < R_RANK; ++r) {
      float term = pw, sum = pw;
#pragma unroll
      for (int m = 1; m <= 6; ++m) {
        term *= hh / (float)(m * (m + r));
        sum += term;
      }
      float c = g * ((r == 0) ? 1.f : 2.f) * sum;
      Wr[((size_t)r * COUTP + o) * CINP + i] = (__bf16)c;
      pw *= h / (float)(r + 1);
    }
  }
}

__global__ void setup_all(const float* __restrict__ x,
                          const float* __restrict__ W1, const float* __restrict__ P1,
                          const float* __restrict__ W2, const float* __restrict__ P2,
                          const float* __restrict__ W3, const float* __restrict__ P3,
                          __bf16* __restrict__ Xb, __bf16* __restrict__ Wr1,
                          __bf16* __restrict__ Wr2, __bf16* __restrict__ Wr3,
                          __bf16* __restrict__ Af, float* __restrict__ stats) {
  int blk = blockIdx.x;
  if (blk < 256) { build_wr_body(W1, P1, Wr1, 700, 704, 256, 256, blk); return; }
  blk -= 256;
  if (blk < 256) { build_wr_body(W2, P2, Wr2, 256, 256, 256, 256, blk); return; }
  blk -= 256;
  if (blk < 32) { build_wr_body(W3, P3, Wr3, 256, 256, 20, 32, blk); return; }
  blk -= 32;
  if (blk < 196) {  // Afir (112 x 448): [t][r*100+s] = PHI[s-t+24][r], else 0
    int idx = blk * 256 + threadIdx.x;
    if (idx < 112 * 448) {
      int t = idx / 448, k = idx - t * 448;
      float v = 0.f;
      if (t < 100 && k < 400) {
        int r = k / 100, s = k - r * 100;
        int tau = s - t + 24;
        if (tau >= 0 && tau < 25) v = PHI.v[tau][r];
      }
      Af[idx] = (__bf16)v;
    }
    return;
  }
  blk -= 196;
  if (blk < 12800) {  // x (B,T,700) f32 -> Xb (T,B,704) bf16
    int t = blk >> 7, b = blk & 127;
    const float* src = x + ((size_t)b * T_LEN + t) * 700;
    __bf16* dst = Xb + (size_t)blk * 704;
    for (int c = threadIdx.x; c < 704; c += 256) dst[c] = (c < 700) ? (__bf16)src[c] : (__bf16)0.f;
    return;
  }
  blk -= 12800;
  if (blk == 0) {
    for (int i = threadIdx.x; i < 1024; i += 256) stats[i] = 0.f;
  }
}

// ---------------------------------------------------------------------------
// Main GEMM, BK=64: Z[k=(r,t)][n=(b,o)] = A @ Wr^T. Pure async-DMA staging.
// LDS: [row][64], 8-elem kgroup slot s holds logical group s^(row&7).
// ---------------------------------------------------------------------------
template <int CINP, int BLK_N, int WROWS, int WCOLS, int CO_SH>
__global__ __launch_bounds__(256, 2)
void gemm_rk64(const __bf16* __restrict__ A, const __bf16* __restrict__ Bm,
               __bf16* __restrict__ Z) {
  constexpr int COUTP = 1 << CO_SH;
  constexpr int WM = 128 / WROWS;
  constexpr int WN = BLK_N / WCOLS;
  constexpr int RM = WM / 16;
  constexpr int RN = WN / 16;
  __shared__ __align__(16) __bf16 sA[128 * 64];
  __shared__ __align__(16) __bf16 sB[BLK_N * 64];

  const int tid = threadIdx.x;
  const int w = tid >> 6, lane = tid & 63;
  const int q = lane >> 4, ln = lane & 15;
  const int wrow = w / WCOLS, wcol = w % WCOLS;
  const int srow8 = lane >> 3;
  const int s8 = lane & 7;

  const int t0 = blockIdx.x;
  const int oc = blockIdx.y * BLK_N;
  const __bf16* Abase = A + (size_t)t0 * 128 * CINP;
  const __bf16* Bbase = Bm + (size_t)oc * CINP;

  v4f acc[RM][RN];
#pragma unroll
  for (int a = 0; a < RM; ++a)
#pragma unroll
    for (int b = 0; b < RN; ++b) acc[a][b] = v4f{0.f, 0.f, 0.f, 0.f};

  for (int ic = 0; ic < CINP; ic += 64) {
    for (int j = w; j < 16; j += 4) {  // A: 128 rows, 8 rows/issue
      int m = j * 8 + srow8;
      int g = s8 ^ (m & 7);
      gl_lds16(Abase + (size_t)m * CINP + ic + g * 8, &sA[j * 512]);
    }
    for (int j = w; j < BLK_N / 8; j += 4) {  // B
      int n = j * 8 + srow8;
      int g = s8 ^ (n & 7);
      gl_lds16(Bbase + (size_t)n * CINP + ic + g * 8, &sB[j * 512]);
    }
    __syncthreads();

#pragma unroll
    for (int s = 0; s < 2; ++s) {
      v8bf af[RM], bfr[RN];
#pragma unroll
      for (int a = 0; a < RM; ++a) {
        int m = wrow * WM + a * 16 + ln;
        af[a] = *(const v8bf*)&sA[m * 64 + ((((s << 2) | q) ^ (m & 7)) * 8)];
      }
#pragma unroll
      for (int b = 0; b < RN; ++b) {
        int n = wcol * WN + b * 16 + ln;
        bfr[b] = *(const v8bf*)&sB[n * 64 + ((((s << 2) | q) ^ (n & 7)) * 8)];
      }
#pragma unroll
      for (int a = 0; a < RM; ++a)
#pragma unroll
        for (int b = 0; b < RN; ++b)
          acc[a][b] = __builtin_amdgcn_mfma_f32_16x16x32_bf16(af[a], bfr[b], acc[a][b], 0, 0, 0);
    }
    __syncthreads();
  }

  // C/D: col=lane&15, row=quad*4+reg (m89-verified)
#pragma unroll
  for (int a = 0; a < RM; ++a) {
#pragma unroll
    for (int b = 0; b < RN; ++b) {
      int n = oc + wcol * WN + b * 16 + ln;
      int r = n >> CO_SH, o = n & (COUTP - 1);
#pragma unroll
      for (int rr = 0; rr < 4; ++rr) {
        int m = t0 * 128 + wrow * WM + a * 16 + q * 4 + rr;
        Z[((size_t)r * M_ROWS + m) * COUTP + o] = (__bf16)acc[a][b][rr];
      }
    }
  }
}

// ---------------------------------------------------------------------------
// FIR GEMM, BK=64, K=448: Y(112 x 64-slice) = Afir(112x448) @ Z(448xN).
// B transposed in LDS (k-pair packed b32, [n][35-dword stride]).
// STATS: fused BN sum/sumsq.  SOFTMAX (L3): in-LDS softmax over o + time-sum.
// ---------------------------------------------------------------------------
template <int COUTP, bool STATS, bool SOFTMAX>
__global__ __launch_bounds__(256, 2)
void fir_gemm64(const __bf16* __restrict__ Af, const __bf16* __restrict__ Z,
                __bf16* __restrict__ Yout, float* __restrict__ stats,
                float* __restrict__ outp, int N) {
  __shared__ __align__(16) unsigned char smem[26624];
  __bf16* sA = (__bf16*)smem;               // 112*64*2 = 14336 B
  uint32* sBu = (uint32*)(smem + 14336);    // 64*35*4  =  8960 B

  const int tid = threadIdx.x;
  const int w = tid >> 6, lane = tid & 63;
  const int q = lane >> 4, ln = lane & 15;
  const int srow8 = lane >> 3, s8 = lane & 7;
  const int kp = tid >> 3;    // 0..31
  const int noct = tid & 7;   // 0..7
  const int nb = blockIdx.x * 64;

  v4f acc[7];
#pragma unroll
  for (int a = 0; a < 7; ++a) acc[a] = v4f{0.f, 0.f, 0.f, 0.f};

  for (int kc = 0; kc < K_FIR; kc += 64) {
    // stage A (112 x 64)
    for (int j = w; j < 14; j += 4) {
      int m = j * 8 + srow8;
      int g = s8 ^ (m & 7);
      gl_lds16(Af + (size_t)m * K_FIR + kc + g * 8, &sA[j * 512]);
    }
    // stage B transposed
    const __bf16* zp = Z + (size_t)(kc + kp * 2) * N + nb + noct * 8;
    uint4 r0 = *(const uint4*)zp;
    uint4 r1 = *(const uint4*)(zp + N);
    const ushort_t* p0 = (const ushort_t*)&r0;
    const ushort_t* p1 = (const ushort_t*)&r1;
#pragma unroll
    for (int j = 0; j < 8; ++j) {
      uint32 val = (uint32)p0[j] | ((uint32)p1[j] << 16);
      sBu[(noct * 8 + j) * 35 + kp] = val;
    }
    __syncthreads();

#pragma unroll
    for (int s = 0; s < 2; ++s) {
      v8bf af[7];
#pragma unroll
      for (int a = 0; a < 7; ++a) {
        int m = a * 16 + ln;
        af[a] = *(const v8bf*)&sA[m * 64 + ((((s << 2) | q) ^ (m & 7)) * 8)];
      }
      int base = (w * 16 + ln) * 35 + s * 16 + q * 4;
      uint32 tmp[4] = {sBu[base], sBu[base + 1], sBu[base + 2], sBu[base + 3]};
      v8bf bfr = *(const v8bf*)tmp;
#pragma unroll
      for (int a = 0; a < 7; ++a)
        acc[a] = __builtin_amdgcn_mfma_f32_16x16x32_bf16(af[a], bfr, acc[a], 0, 0, 0);
    }
    __syncthreads();
  }

  int ng = nb + w * 16 + ln;
  if (!SOFTMAX) {
    float s = 0.f, ss = 0.f;
#pragma unroll
    for (int a = 0; a < 7; ++a) {
#pragma unroll
      for (int rr = 0; rr < 4; ++rr) {
        int t = a * 16 + q * 4 + rr;
        float v = acc[a][rr];
        if (t < 100) {
          Yout[(size_t)t * N + ng] = (__bf16)v;
          s += v; ss += v * v;
        }
      }
    }
    if (STATS) {
      s += __shfl_xor(s, 16); ss += __shfl_xor(ss, 16);
      s += __shfl_xor(s, 32); ss += __shfl_xor(ss, 32);
      if (q == 0) {
        int o = ng & (COUTP - 1);
        atomicAdd(&stats[o], s);
        atomicAdd(&stats[COUTP + o], ss);
      }
    }
  } else {
    // L3: this block holds all t and all o for 2 batch entries.
    float* smx = (float*)smem;               // [100][65] = 26000 B (reuses sA/sB)
    float* lacc = (float*)(smem + 26000);    // 40 floats
    int col = w * 16 + ln;
#pragma unroll
    for (int a = 0; a < 7; ++a) {
#pragma unroll
      for (int rr = 0; rr < 4; ++rr) {
        int t = a * 16 + q * 4 + rr;
        if (t < 100) smx[t * 65 + col] = acc[a][rr];
      }
    }
    if (tid < 64) lacc[tid & 63] = 0.f;
    __syncthreads();
    if (tid < 200) {
      int bl = tid / 100, t = tid - bl * 100;
      const float* rr = &smx[t * 65 + bl * 32];
      float v[20], m = -1e30f;
#pragma unroll
      for (int o = 0; o < 20; ++o) { v[o] = rr[o]; m = fmaxf(m, v[o]); }
      float sum = 0.f;
#pragma unroll
      for (int o = 0; o < 20; ++o) { v[o] = expf(v[o] - m); sum += v[o]; }
      float inv = 1.f / sum;
#pragma unroll
      for (int o = 0; o < 20; ++o) atomicAdd(&lacc[bl * 20 + o], v[o] * inv);
    }
    __syncthreads();
    if (tid < 40) {
      int bl = tid / 20, o = tid - bl * 20;
      int b = (nb >> 5) + bl;
      outp[b * 20 + o] = lacc[bl * 20 + o];
    }
  }
}

// normalize + relu, bf16x8 vectorized, in-place on Y
__global__ __launch_bounds__(256)
void bn_apply_relu8(__bf16* __restrict__ h, const float* __restrict__ stats,
                    const float* __restrict__ gamma, const float* __restrict__ beta) {
  int idx = blockIdx.x * 256 + threadIdx.x;
  int co = (idx & 31) * 8;
  size_t row = (size_t)(idx >> 5);
  __bf16* p = h + row * 256 + co;
  uint4 raw = *(const uint4*)p;
  const ushort_t* pr = (const ushort_t*)&raw;
  uint4 outv;
  ushort_t* po = (ushort_t*)&outv;
#pragma unroll
  for (int j = 0; j < 8; ++j) {
    int c = co + j;
    float mean = stats[c] * (1.f / 12800.f);
    float var = stats[256 + c] * (1.f / 12800.f) - mean * mean;
    float inv = rsqrtf(var + 1e-5f) * gamma[c];
    uint32 u = (uint32)pr[j] << 16;
    float xv; __builtin_memcpy(&xv, &u, 4);
    float v = (xv - mean) * inv + beta[c];
    v = fmaxf(v, 0.f);
    __bf16 bv = (__bf16)v;
    po[j] = *(const ushort_t*)&bv;
  }
  *(uint4*)p = outv;
}

// ---------------------------------------------------------------------------

extern "C" void kernel_launch(void* const* d_in, const int* in_sizes, int n_in,
                              void* d_out, int out_size, void* d_ws, size_t ws_size,
                              hipStream_t stream) {
  const float* x  = (const float*)d_in[0];
  const float* W1 = (const float*)d_in[1];
  const float* P1 = (const float*)d_in[2];
  const float* W2 = (const float*)d_in[3];
  const float* P2 = (const float*)d_in[4];
  const float* W3 = (const float*)d_in[5];
  const float* P3 = (const float*)d_in[6];
  const float* g1 = (const float*)d_in[7];
  const float* b1 = (const float*)d_in[8];
  const float* g2 = (const float*)d_in[9];
  const float* b2 = (const float*)d_in[10];
  float* out = (float*)d_out;

  constexpr size_t XB_B  = (size_t)M_ROWS * 704 * 2;        // 18,022,400
  constexpr size_t Z_B   = (size_t)K_FIR * 32768 * 2;       // 29,360,128
  constexpr size_t Y12_B = (size_t)M_ROWS * 256 * 2;        //  6,553,600
  constexpr size_t W1_B  = (size_t)R_RANK * 256 * 704 * 2;  //  1,441,792
  constexpr size_t W2_B  = (size_t)R_RANK * 256 * 256 * 2;  //    524,288
  constexpr size_t W3_B  = (size_t)R_RANK * 32 * 256 * 2;   //     65,536
  constexpr size_t AF_B  = (size_t)112 * K_FIR * 2;         //    100,352
  constexpr size_t ST_B  = 4096;
  constexpr size_t TOTAL = XB_B + Z_B + Y12_B + W1_B + W2_B + W3_B + AF_B + ST_B;
  if (ws_size < TOTAL) return;

  char* ws = (char*)d_ws;
  size_t off = 0;
  __bf16* Xb   = (__bf16*)(ws + off); off += XB_B;
  __bf16* Zb   = (__bf16*)(ws + off); off += Z_B;
  __bf16* Yb   = (__bf16*)(ws + off); off += Y12_B;   // Y1 then Y2 (in-place BN)
  __bf16* Wr1  = (__bf16*)(ws + off); off += W1_B;
  __bf16* Wr2  = (__bf16*)(ws + off); off += W2_B;
  __bf16* Wr3  = (__bf16*)(ws + off); off += W3_B;
  __bf16* Afir = (__bf16*)(ws + off); off += AF_B;
  float*  stats1 = (float*)(ws + off);
  float*  stats2 = stats1 + 512;

  // fused setup: 256+256+32+196+12800+1 blocks
  setup_all<<<dim3(13541), 256, 0, stream>>>(x, W1, P1, W2, P2, W3, P3,
                                             Xb, Wr1, Wr2, Wr3, Afir, stats1);

  // layer 1: GEMM (12800 x 1024 x 704), BLK_N=256 -> FIR (+stats) -> BN in-place
  gemm_rk64<704, 256, 2, 2, 8><<<dim3(100, 4), 256, 0, stream>>>(Xb, Wr1, Zb);
  fir_gemm64<256, true, false><<<dim3(512), 256, 0, stream>>>(
      Afir, Zb, Yb, stats1, nullptr, 32768);
  bn_apply_relu8<<<dim3(1600), 256, 0, stream>>>(Yb, stats1, g1, b1);

  // layer 2: GEMM (12800 x 1024 x 256), BLK_N=256
  gemm_rk64<256, 256, 2, 2, 8><<<dim3(100, 4), 256, 0, stream>>>(Yb, Wr2, Zb);
  fir_gemm64<256, true, false><<<dim3(512), 256, 0, stream>>>(
      Afir, Zb, Yb, stats2, nullptr, 32768);
  bn_apply_relu8<<<dim3(1600), 256, 0, stream>>>(Yb, stats2, g2, b2);

  // layer 3: GEMM (12800 x 128 x 256), then FIR + fused softmax/time-sum
  gemm_rk64<256, 64, 2, 2, 5><<<dim3(100, 2), 256, 0, stream>>>(Yb, Wr3, Zb);
  fir_gemm64<32, false, true><<<dim3(64), 256, 0, stream>>>(
      Afir, Zb, nullptr, nullptr, out, 4096);
}